// Round 1
// baseline (2744.164 us; speedup 1.0000x reference)
//
#include <hip/hip_runtime.h>
#include <math.h>

#define N_NODES  20000
#define N_EDGES  320000
#define N_GRAPHS 200
#define MAXN     100
#define F_IN     128
#define F_H      256
#define F_L      64
#define P_PAIRS  4950
#define ADJ_SIZE (N_GRAPHS * MAXN * MAXN)   // 2,000,000
#define MU_OFF   ADJ_SIZE
#define LV_OFF   (ADJ_SIZE + N_GRAPHS * F_L)

static inline int ceil_div(int a, int b) { return (a + b - 1) / b; }

// ---------------------------------------------------------------- degree
__global__ __launch_bounds__(256) void k_deg(const int* __restrict__ dst,
                                             float* __restrict__ deg, int nE) {
    int i = blockIdx.x * blockDim.x + threadIdx.x;
    if (i < nE) atomicAdd(deg + dst[i], 1.0f);
}

__global__ __launch_bounds__(256) void k_dinv(float* __restrict__ deg, int n) {
    int i = blockIdx.x * blockDim.x + threadIdx.x;
    if (i < n) deg[i] = rsqrtf(deg[i] + 1.0f);   // +1 self-loop; deg>=1 always
}

// ---------------------------------------------------------------- tiled fp32 GEMM
// C[M,N] = A[M,K] @ B[K,N], row-major. BM=BN=64, BK=16, 256 threads, 4x4/thread.
#define BM 64
#define BN 64
#define BKK 16
__global__ __launch_bounds__(256) void k_gemm(const float* __restrict__ A,
                                              const float* __restrict__ B,
                                              float* __restrict__ C,
                                              int M, int N, int K) {
    __shared__ float As[BKK][BM + 1];
    __shared__ float Bs[BKK][BN + 1];
    int bm = blockIdx.y * BM;
    int bn = blockIdx.x * BN;
    int tid = threadIdx.x;
    int tx = tid & 15, ty = tid >> 4;
    float acc[4][4] = {};
    for (int k0 = 0; k0 < K; k0 += BKK) {
        #pragma unroll
        for (int i = 0; i < 4; ++i) {
            int lin = tid + 256 * i;       // 0..1023
            int m = lin / BKK, kk = lin % BKK;
            int gm = bm + m;
            As[kk][m] = (gm < M) ? A[(size_t)gm * K + k0 + kk] : 0.0f;
        }
        #pragma unroll
        for (int i = 0; i < 4; ++i) {
            int lin = tid + 256 * i;
            int kk = lin / BN, n = lin % BN;
            Bs[kk][n] = B[(size_t)(k0 + kk) * N + bn + n];
        }
        __syncthreads();
        #pragma unroll
        for (int kk = 0; kk < BKK; ++kk) {
            float a[4], b[4];
            #pragma unroll
            for (int i = 0; i < 4; ++i) a[i] = As[kk][ty * 4 + i];
            #pragma unroll
            for (int j = 0; j < 4; ++j) b[j] = Bs[kk][tx * 4 + j];
            #pragma unroll
            for (int i = 0; i < 4; ++i)
                #pragma unroll
                for (int j = 0; j < 4; ++j) acc[i][j] += a[i] * b[j];
        }
        __syncthreads();
    }
    #pragma unroll
    for (int i = 0; i < 4; ++i) {
        int gm = bm + ty * 4 + i;
        if (gm >= M) continue;
        #pragma unroll
        for (int j = 0; j < 4; ++j)
            C[(size_t)gm * N + bn + tx * 4 + j] = acc[i][j];
    }
}

// ---------------------------------------------------------------- row scale: hs = H * dinv[row]
__global__ __launch_bounds__(256) void k_scale(const float* __restrict__ H,
                                               const float* __restrict__ dinv,
                                               float* __restrict__ hs) {
    int i = blockIdx.x * blockDim.x + threadIdx.x;   // per float4; F_H/4 = 64 per row
    if (i >= N_NODES * (F_H / 4)) return;
    int v = i >> 6;
    float s = dinv[v];
    float4 h = ((const float4*)H)[i];
    h.x *= s; h.y *= s; h.z *= s; h.w *= s;
    ((float4*)hs)[i] = h;
}

// ---------------------------------------------------------------- edge scatter (atomic)
// 64 lanes per edge; lane covers 4 contiguous features.
__global__ __launch_bounds__(256) void k_scatter(const int* __restrict__ src,
                                                 const int* __restrict__ dst,
                                                 const float* __restrict__ hs,
                                                 float* __restrict__ acc, int nE) {
    int e = blockIdx.x * (blockDim.x >> 6) + (threadIdx.x >> 6);
    if (e >= nE) return;
    int lane = threadIdx.x & 63;
    int s = src[e], d = dst[e];
    float4 v = ((const float4*)(hs + (size_t)s * F_H))[lane];
    float* o = acc + (size_t)d * F_H + lane * 4;
    atomicAdd(o + 0, v.x);
    atomicAdd(o + 1, v.y);
    atomicAdd(o + 2, v.z);
    atomicAdd(o + 3, v.w);
}

// ---------------------------------------------------------------- out = relu(dinv*(acc + dinv*H) + b)
__global__ __launch_bounds__(256) void k_finish(const float* __restrict__ H,
                                                const float* __restrict__ acc,
                                                const float* __restrict__ dinv,
                                                const float* __restrict__ bias,
                                                float* __restrict__ out) {
    int i = blockIdx.x * blockDim.x + threadIdx.x;
    if (i >= N_NODES * (F_H / 4)) return;
    int v = i >> 6, f4 = i & 63;
    float s = dinv[v];
    float4 h = ((const float4*)H)[i];
    float4 a = ((const float4*)acc)[i];
    float4 b = ((const float4*)bias)[f4];
    float4 o;
    o.x = fmaxf(s * (a.x + s * h.x) + b.x, 0.0f);
    o.y = fmaxf(s * (a.y + s * h.y) + b.y, 0.0f);
    o.z = fmaxf(s * (a.z + s * h.z) + b.z, 0.0f);
    o.w = fmaxf(s * (a.w + s * h.w) + b.w, 0.0f);
    ((float4*)out)[i] = o;
}

// ---------------------------------------------------------------- mean pool
__global__ __launch_bounds__(256) void k_pool(const float* __restrict__ h,
                                              const int* __restrict__ batch,
                                              float* __restrict__ hg,
                                              float* __restrict__ cnt) {
    int i = blockIdx.x * blockDim.x + threadIdx.x;
    if (i >= N_NODES * (F_H / 4)) return;
    int v = i >> 6, f4 = i & 63;
    int g = batch[v];
    float4 x = ((const float4*)h)[i];
    float* o = hg + (size_t)g * F_H + f4 * 4;
    atomicAdd(o + 0, x.x);
    atomicAdd(o + 1, x.y);
    atomicAdd(o + 2, x.z);
    atomicAdd(o + 3, x.w);
    if (f4 == 0) atomicAdd(cnt + g, 1.0f);
}

__global__ __launch_bounds__(256) void k_pooldiv(float* __restrict__ hg,
                                                 const float* __restrict__ cnt) {
    int i = blockIdx.x * blockDim.x + threadIdx.x;
    if (i >= N_GRAPHS * F_H) return;
    int g = i >> 8;
    hg[i] /= fmaxf(cnt[g], 1.0f);
}

// ---------------------------------------------------------------- VAE head: mu, logvar, z
__global__ __launch_bounds__(256) void k_head(const float* __restrict__ hg,
                                              const float* __restrict__ Wmu,
                                              const float* __restrict__ bmu,
                                              const float* __restrict__ Wlv,
                                              const float* __restrict__ blv,
                                              const float* __restrict__ eps,
                                              float* __restrict__ out,
                                              float* __restrict__ z) {
    int i = blockIdx.x * blockDim.x + threadIdx.x;
    if (i >= N_GRAPHS * F_L) return;
    int g = i / F_L, l = i % F_L;
    const float* hr = hg + (size_t)g * F_H;
    float smu = 0.0f, slv = 0.0f;
    for (int k = 0; k < F_H; ++k) {
        float h = hr[k];
        smu += h * Wmu[k * F_L + l];
        slv += h * Wlv[k * F_L + l];
    }
    smu += bmu[l];
    slv += blv[l];
    out[MU_OFF + i] = smu;
    out[LV_OFF + i] = slv;
    z[i] = smu + eps[i] * expf(0.5f * slv);
}

// ---------------------------------------------------------------- small dense layer
// Y[g,n] = act(X[g,:K] @ W[K,N] + b[n]); act 0=relu, 1=sigmoid
__global__ __launch_bounds__(256) void k_dec(const float* __restrict__ X,
                                             const float* __restrict__ W,
                                             const float* __restrict__ b,
                                             float* __restrict__ Y,
                                             int K, int N, int act) {
    int i = blockIdx.x * blockDim.x + threadIdx.x;
    if (i >= N_GRAPHS * N) return;
    int g = i / N, n = i % N;
    const float* xr = X + (size_t)g * K;
    float s = 0.0f;
    for (int k = 0; k < K; ++k) s += xr[k] * W[(size_t)k * N + n];
    s += b[n];
    Y[i] = (act == 0) ? fmaxf(s, 0.0f) : 1.0f / (1.0f + expf(-s));
}

// ---------------------------------------------------------------- adjacency expansion
__global__ __launch_bounds__(256) void k_adj(const float* __restrict__ probs,
                                             float* __restrict__ adj) {
    int i = blockIdx.x * blockDim.x + threadIdx.x;
    if (i >= ADJ_SIZE) return;
    int g = i / (MAXN * MAXN);
    int r = i % (MAXN * MAXN);
    int a = r / MAXN, b = r % MAXN;
    float v = 0.0f;
    if (a != b) {
        int lo = min(a, b), hi = max(a, b);
        int p = lo * (MAXN - 1) - (lo * (lo - 1)) / 2 + (hi - lo - 1);
        v = probs[(size_t)g * P_PAIRS + p];
    }
    adj[i] = v;
}

// ================================================================ launch
extern "C" void kernel_launch(void* const* d_in, const int* in_sizes, int n_in,
                              void* d_out, int out_size, void* d_ws, size_t ws_size,
                              hipStream_t stream) {
    const float* x    = (const float*)d_in[0];
    const int*   eidx = (const int*)d_in[1];
    const int*   batch= (const int*)d_in[2];
    const float* eps  = (const float*)d_in[3];
    const float* W1   = (const float*)d_in[4];
    const float* b1   = (const float*)d_in[5];
    const float* W2   = (const float*)d_in[6];
    const float* b2   = (const float*)d_in[7];
    const float* Wmu  = (const float*)d_in[8];
    const float* bmu  = (const float*)d_in[9];
    const float* Wlv  = (const float*)d_in[10];
    const float* blv  = (const float*)d_in[11];
    const float* D1   = (const float*)d_in[12];
    const float* db1  = (const float*)d_in[13];
    const float* D2   = (const float*)d_in[14];
    const float* db2  = (const float*)d_in[15];
    const float* D3   = (const float*)d_in[16];
    const float* db3  = (const float*)d_in[17];

    const int* src = eidx;
    const int* dst = eidx + N_EDGES;
    float* out = (float*)d_out;

    // workspace carve-up (floats)
    float* ws   = (float*)d_ws;
    size_t o = 0;
    float* dinv = ws + o; o += 20480;                 // 20000, padded
    float* bufA = ws + o; o += (size_t)N_NODES * F_H; // x@W / h@W
    float* bufB = ws + o; o += (size_t)N_NODES * F_H; // scaled rows / layer out
    float* bufC = ws + o; o += (size_t)N_NODES * F_H; // scatter accumulator
    float* hg   = ws + o; o += (size_t)N_GRAPHS * F_H;
    float* cnt  = ws + o; o += 256;
    float* z    = ws + o; o += (size_t)N_GRAPHS * F_L;
    float* d1   = ws + o; o += (size_t)N_GRAPHS * F_H;
    float* d2   = ws + o; o += (size_t)N_GRAPHS * F_H;
    float* probs= ws + o; o += (size_t)N_GRAPHS * P_PAIRS;

    const int nodeVec = N_NODES * (F_H / 4);          // 1,280,000 float4 threads
    const size_t hbytes = (size_t)N_NODES * F_H * sizeof(float);

    // degree -> dinv (shared by both layers)
    hipMemsetAsync(dinv, 0, N_NODES * sizeof(float), stream);
    k_deg<<<ceil_div(N_EDGES, 256), 256, 0, stream>>>(dst, dinv, N_EDGES);
    k_dinv<<<ceil_div(N_NODES, 256), 256, 0, stream>>>(dinv, N_NODES);

    // ---- GCN layer 1
    {
        dim3 grid(F_H / BN, ceil_div(N_NODES, BM));
        k_gemm<<<grid, 256, 0, stream>>>(x, W1, bufA, N_NODES, F_H, F_IN);
    }
    k_scale<<<ceil_div(nodeVec, 256), 256, 0, stream>>>(bufA, dinv, bufB);
    hipMemsetAsync(bufC, 0, hbytes, stream);
    k_scatter<<<ceil_div(N_EDGES, 4), 256, 0, stream>>>(src, dst, bufB, bufC, N_EDGES);
    k_finish<<<ceil_div(nodeVec, 256), 256, 0, stream>>>(bufA, bufC, dinv, b1, bufB);

    // ---- GCN layer 2
    {
        dim3 grid(F_H / BN, ceil_div(N_NODES, BM));
        k_gemm<<<grid, 256, 0, stream>>>(bufB, W2, bufA, N_NODES, F_H, F_H);
    }
    k_scale<<<ceil_div(nodeVec, 256), 256, 0, stream>>>(bufA, dinv, bufB);
    hipMemsetAsync(bufC, 0, hbytes, stream);
    k_scatter<<<ceil_div(N_EDGES, 4), 256, 0, stream>>>(src, dst, bufB, bufC, N_EDGES);
    k_finish<<<ceil_div(nodeVec, 256), 256, 0, stream>>>(bufA, bufC, dinv, b2, bufB);

    // ---- global mean pool
    hipMemsetAsync(hg, 0, (size_t)N_GRAPHS * F_H * sizeof(float), stream);
    hipMemsetAsync(cnt, 0, 256 * sizeof(float), stream);
    k_pool<<<ceil_div(nodeVec, 256), 256, 0, stream>>>(bufB, batch, hg, cnt);
    k_pooldiv<<<ceil_div(N_GRAPHS * F_H, 256), 256, 0, stream>>>(hg, cnt);

    // ---- VAE head + decoder
    k_head<<<ceil_div(N_GRAPHS * F_L, 256), 256, 0, stream>>>(hg, Wmu, bmu, Wlv, blv, eps, out, z);
    k_dec<<<ceil_div(N_GRAPHS * F_H, 256), 256, 0, stream>>>(z, D1, db1, d1, F_L, F_H, 0);
    k_dec<<<ceil_div(N_GRAPHS * F_H, 256), 256, 0, stream>>>(d1, D2, db2, d2, F_H, F_H, 0);
    k_dec<<<ceil_div(N_GRAPHS * P_PAIRS, 256), 256, 0, stream>>>(d2, D3, db3, probs, F_H, P_PAIRS, 1);

    // ---- adjacency expansion
    k_adj<<<ceil_div(ADJ_SIZE, 256), 256, 0, stream>>>(probs, out);
}

// Round 2
// 776.463 us; speedup vs baseline: 3.5342x; 3.5342x over previous
//
#include <hip/hip_runtime.h>
#include <math.h>

#define N_NODES  20000
#define N_EDGES  320000
#define N_GRAPHS 200
#define MAXN     100
#define F_IN     128
#define F_H      256
#define F_L      64
#define P_PAIRS  4950
#define ADJ_SIZE (N_GRAPHS * MAXN * MAXN)   // 2,000,000
#define MU_OFF   ADJ_SIZE
#define LV_OFF   (ADJ_SIZE + N_GRAPHS * F_L)

static inline int ceil_div(int a, int b) { return (a + b - 1) / b; }

// ---------------------------------------------------------------- degree histogram (int)
__global__ __launch_bounds__(256) void k_deg(const int* __restrict__ dst,
                                             int* __restrict__ deg, int nE) {
    int i = blockIdx.x * blockDim.x + threadIdx.x;
    if (i < nE) atomicAdd(deg + dst[i], 1);
}

__global__ __launch_bounds__(256) void k_dinv(const int* __restrict__ deg,
                                              float* __restrict__ dinv, int n) {
    int i = blockIdx.x * blockDim.x + threadIdx.x;
    if (i < n) dinv[i] = rsqrtf((float)deg[i] + 1.0f);   // +1 self-loop
}

// ---------------------------------------------------------------- exclusive scan (single block)
__global__ __launch_bounds__(256) void k_scan(const int* __restrict__ deg,
                                              int* __restrict__ rowptr, int n) {
    __shared__ int tmp[256];
    __shared__ int carry;
    if (threadIdx.x == 0) carry = 0;
    __syncthreads();
    for (int base = 0; base < n; base += 256) {
        int i = base + threadIdx.x;
        int v = (i < n) ? deg[i] : 0;
        tmp[threadIdx.x] = v;
        __syncthreads();
        int c = carry;
        #pragma unroll
        for (int off = 1; off < 256; off <<= 1) {
            int t = (threadIdx.x >= (unsigned)off) ? tmp[threadIdx.x - off] : 0;
            __syncthreads();
            tmp[threadIdx.x] += t;
            __syncthreads();
        }
        if (i < n) rowptr[i + 1] = c + tmp[threadIdx.x];
        if (threadIdx.x == 255) carry = c + tmp[255];
        __syncthreads();
    }
    if (threadIdx.x == 0) rowptr[0] = 0;
}

// ---------------------------------------------------------------- CSR fill
__global__ __launch_bounds__(256) void k_fill(const int* __restrict__ src,
                                              const int* __restrict__ dst,
                                              const int* __restrict__ rowptr,
                                              int* __restrict__ fill,
                                              int* __restrict__ col, int nE) {
    int e = blockIdx.x * blockDim.x + threadIdx.x;
    if (e >= nE) return;
    int d = dst[e];
    int pos = rowptr[d] + atomicAdd(fill + d, 1);
    col[pos] = src[e];
}

// ---------------------------------------------------------------- tiled fp32 GEMM
// C[M,N] = A[M,K] @ B[K,N], row-major. BM=BN=64, BK=16, 256 threads, 4x4/thread.
#define BM 64
#define BN 64
#define BKK 16
__global__ __launch_bounds__(256) void k_gemm(const float* __restrict__ A,
                                              const float* __restrict__ B,
                                              float* __restrict__ C,
                                              int M, int N, int K) {
    __shared__ float As[BKK][BM + 1];
    __shared__ float Bs[BKK][BN + 1];
    int bm = blockIdx.y * BM;
    int bn = blockIdx.x * BN;
    int tid = threadIdx.x;
    int tx = tid & 15, ty = tid >> 4;
    float acc[4][4] = {};
    for (int k0 = 0; k0 < K; k0 += BKK) {
        #pragma unroll
        for (int i = 0; i < 4; ++i) {
            int lin = tid + 256 * i;       // 0..1023
            int m = lin / BKK, kk = lin % BKK;
            int gm = bm + m;
            As[kk][m] = (gm < M) ? A[(size_t)gm * K + k0 + kk] : 0.0f;
        }
        #pragma unroll
        for (int i = 0; i < 4; ++i) {
            int lin = tid + 256 * i;
            int kk = lin / BN, n = lin % BN;
            Bs[kk][n] = B[(size_t)(k0 + kk) * N + bn + n];
        }
        __syncthreads();
        #pragma unroll
        for (int kk = 0; kk < BKK; ++kk) {
            float a[4], b[4];
            #pragma unroll
            for (int i = 0; i < 4; ++i) a[i] = As[kk][ty * 4 + i];
            #pragma unroll
            for (int j = 0; j < 4; ++j) b[j] = Bs[kk][tx * 4 + j];
            #pragma unroll
            for (int i = 0; i < 4; ++i)
                #pragma unroll
                for (int j = 0; j < 4; ++j) acc[i][j] += a[i] * b[j];
        }
        __syncthreads();
    }
    #pragma unroll
    for (int i = 0; i < 4; ++i) {
        int gm = bm + ty * 4 + i;
        if (gm >= M) continue;
        #pragma unroll
        for (int j = 0; j < 4; ++j)
            C[(size_t)gm * N + bn + tx * 4 + j] = acc[i][j];
    }
}

// ---------------------------------------------------------------- fused GCN aggregate
// out[v] = relu(dinv[v] * (sum_{s in N(v)} dinv[s]*H[s] + dinv[v]*H[v]) + bias)
// one wave per node; lane covers 4 contiguous features (float4).
__global__ __launch_bounds__(256) void k_gather(const float* __restrict__ H,
                                                const int* __restrict__ rowptr,
                                                const int* __restrict__ col,
                                                const float* __restrict__ dinv,
                                                const float* __restrict__ bias,
                                                float* __restrict__ out) {
    int v = blockIdx.x * 4 + (threadIdx.x >> 6);
    if (v >= N_NODES) return;
    int lane = threadIdx.x & 63;
    int beg = rowptr[v], end = rowptr[v + 1];
    float4 acc = make_float4(0.f, 0.f, 0.f, 0.f);
    for (int i = beg; i < end; ++i) {
        int s = col[i];
        float sc = dinv[s];
        float4 h = ((const float4*)(H + (size_t)s * F_H))[lane];
        acc.x += sc * h.x; acc.y += sc * h.y;
        acc.z += sc * h.z; acc.w += sc * h.w;
    }
    float dv = dinv[v];
    float4 h = ((const float4*)(H + (size_t)v * F_H))[lane];
    float4 b = ((const float4*)bias)[lane];
    float4 o;
    o.x = fmaxf(dv * (acc.x + dv * h.x) + b.x, 0.0f);
    o.y = fmaxf(dv * (acc.y + dv * h.y) + b.y, 0.0f);
    o.z = fmaxf(dv * (acc.z + dv * h.z) + b.z, 0.0f);
    o.w = fmaxf(dv * (acc.w + dv * h.w) + b.w, 0.0f);
    ((float4*)(out + (size_t)v * F_H))[lane] = o;
}

// ---------------------------------------------------------------- mean pool
__global__ __launch_bounds__(256) void k_pool(const float* __restrict__ h,
                                              const int* __restrict__ batch,
                                              float* __restrict__ hg,
                                              float* __restrict__ cnt) {
    int i = blockIdx.x * blockDim.x + threadIdx.x;
    if (i >= N_NODES * (F_H / 4)) return;
    int v = i >> 6, f4 = i & 63;
    int g = batch[v];
    float4 x = ((const float4*)h)[i];
    float* o = hg + (size_t)g * F_H + f4 * 4;
    atomicAdd(o + 0, x.x);
    atomicAdd(o + 1, x.y);
    atomicAdd(o + 2, x.z);
    atomicAdd(o + 3, x.w);
    if (f4 == 0) atomicAdd(cnt + g, 1.0f);
}

__global__ __launch_bounds__(256) void k_pooldiv(float* __restrict__ hg,
                                                 const float* __restrict__ cnt) {
    int i = blockIdx.x * blockDim.x + threadIdx.x;
    if (i >= N_GRAPHS * F_H) return;
    int g = i >> 8;
    hg[i] /= fmaxf(cnt[g], 1.0f);
}

// ---------------------------------------------------------------- VAE head: mu, logvar, z
__global__ __launch_bounds__(256) void k_head(const float* __restrict__ hg,
                                              const float* __restrict__ Wmu,
                                              const float* __restrict__ bmu,
                                              const float* __restrict__ Wlv,
                                              const float* __restrict__ blv,
                                              const float* __restrict__ eps,
                                              float* __restrict__ out,
                                              float* __restrict__ z) {
    int i = blockIdx.x * blockDim.x + threadIdx.x;
    if (i >= N_GRAPHS * F_L) return;
    int g = i / F_L, l = i % F_L;
    const float* hr = hg + (size_t)g * F_H;
    float smu = 0.0f, slv = 0.0f;
    for (int k = 0; k < F_H; ++k) {
        float h = hr[k];
        smu += h * Wmu[k * F_L + l];
        slv += h * Wlv[k * F_L + l];
    }
    smu += bmu[l];
    slv += blv[l];
    out[MU_OFF + i] = smu;
    out[LV_OFF + i] = slv;
    z[i] = smu + eps[i] * expf(0.5f * slv);
}

// ---------------------------------------------------------------- small dense layer
// Y[g,n] = act(X[g,:K] @ W[K,N] + b[n]); act 0=relu, 1=sigmoid
__global__ __launch_bounds__(256) void k_dec(const float* __restrict__ X,
                                             const float* __restrict__ W,
                                             const float* __restrict__ b,
                                             float* __restrict__ Y,
                                             int K, int N, int act) {
    int i = blockIdx.x * blockDim.x + threadIdx.x;
    if (i >= N_GRAPHS * N) return;
    int g = i / N, n = i % N;
    const float* xr = X + (size_t)g * K;
    float s = 0.0f;
    for (int k = 0; k < K; ++k) s += xr[k] * W[(size_t)k * N + n];
    s += b[n];
    Y[i] = (act == 0) ? fmaxf(s, 0.0f) : 1.0f / (1.0f + expf(-s));
}

// ---------------------------------------------------------------- adjacency expansion
__global__ __launch_bounds__(256) void k_adj(const float* __restrict__ probs,
                                             float* __restrict__ adj) {
    int i = blockIdx.x * blockDim.x + threadIdx.x;
    if (i >= ADJ_SIZE) return;
    int g = i / (MAXN * MAXN);
    int r = i % (MAXN * MAXN);
    int a = r / MAXN, b = r % MAXN;
    float v = 0.0f;
    if (a != b) {
        int lo = min(a, b), hi = max(a, b);
        int p = lo * (MAXN - 1) - (lo * (lo - 1)) / 2 + (hi - lo - 1);
        v = probs[(size_t)g * P_PAIRS + p];
    }
    adj[i] = v;
}

// ================================================================ launch
extern "C" void kernel_launch(void* const* d_in, const int* in_sizes, int n_in,
                              void* d_out, int out_size, void* d_ws, size_t ws_size,
                              hipStream_t stream) {
    const float* x    = (const float*)d_in[0];
    const int*   eidx = (const int*)d_in[1];
    const int*   batch= (const int*)d_in[2];
    const float* eps  = (const float*)d_in[3];
    const float* W1   = (const float*)d_in[4];
    const float* b1   = (const float*)d_in[5];
    const float* W2   = (const float*)d_in[6];
    const float* b2   = (const float*)d_in[7];
    const float* Wmu  = (const float*)d_in[8];
    const float* bmu  = (const float*)d_in[9];
    const float* Wlv  = (const float*)d_in[10];
    const float* blv  = (const float*)d_in[11];
    const float* D1   = (const float*)d_in[12];
    const float* db1  = (const float*)d_in[13];
    const float* D2   = (const float*)d_in[14];
    const float* db2  = (const float*)d_in[15];
    const float* D3   = (const float*)d_in[16];
    const float* db3  = (const float*)d_in[17];

    const int* src = eidx;
    const int* dst = eidx + N_EDGES;
    float* out = (float*)d_out;

    // workspace carve-up
    char* wsb = (char*)d_ws;
    size_t o = 0;
    auto carve = [&](size_t bytes) { void* p = wsb + o; o += (bytes + 255) & ~255ull; return p; };
    int*   deg    = (int*)  carve(N_NODES * sizeof(int));
    int*   fill   = (int*)  carve(N_NODES * sizeof(int));
    int*   rowptr = (int*)  carve((N_NODES + 1) * sizeof(int));
    int*   col    = (int*)  carve(N_EDGES * sizeof(int));
    float* dinv   = (float*)carve(N_NODES * sizeof(float));
    float* bufA   = (float*)carve((size_t)N_NODES * F_H * sizeof(float));
    float* bufB   = (float*)carve((size_t)N_NODES * F_H * sizeof(float));
    float* hg     = (float*)carve((size_t)N_GRAPHS * F_H * sizeof(float));
    float* cnt    = (float*)carve(256 * sizeof(float));
    float* z      = (float*)carve((size_t)N_GRAPHS * F_L * sizeof(float));
    float* d1     = (float*)carve((size_t)N_GRAPHS * F_H * sizeof(float));
    float* d2     = (float*)carve((size_t)N_GRAPHS * F_H * sizeof(float));
    float* probs  = (float*)carve((size_t)N_GRAPHS * P_PAIRS * sizeof(float));

    // ---- CSR build (shared by both layers)
    hipMemsetAsync(deg, 0, N_NODES * sizeof(int), stream);
    hipMemsetAsync(fill, 0, N_NODES * sizeof(int), stream);
    k_deg<<<ceil_div(N_EDGES, 256), 256, 0, stream>>>(dst, deg, N_EDGES);
    k_scan<<<1, 256, 0, stream>>>(deg, rowptr, N_NODES);
    k_dinv<<<ceil_div(N_NODES, 256), 256, 0, stream>>>(deg, dinv, N_NODES);
    k_fill<<<ceil_div(N_EDGES, 256), 256, 0, stream>>>(src, dst, rowptr, fill, col, N_EDGES);

    // ---- GCN layer 1: GEMM + fused aggregate
    {
        dim3 grid(F_H / BN, ceil_div(N_NODES, BM));
        k_gemm<<<grid, 256, 0, stream>>>(x, W1, bufA, N_NODES, F_H, F_IN);
    }
    k_gather<<<ceil_div(N_NODES, 4), 256, 0, stream>>>(bufA, rowptr, col, dinv, b1, bufB);

    // ---- GCN layer 2
    {
        dim3 grid(F_H / BN, ceil_div(N_NODES, BM));
        k_gemm<<<grid, 256, 0, stream>>>(bufB, W2, bufA, N_NODES, F_H, F_H);
    }
    k_gather<<<ceil_div(N_NODES, 4), 256, 0, stream>>>(bufA, rowptr, col, dinv, b2, bufB);

    // ---- global mean pool
    hipMemsetAsync(hg, 0, (size_t)N_GRAPHS * F_H * sizeof(float), stream);
    hipMemsetAsync(cnt, 0, 256 * sizeof(float), stream);
    k_pool<<<ceil_div(N_NODES * (F_H / 4), 256), 256, 0, stream>>>(bufB, batch, hg, cnt);
    k_pooldiv<<<ceil_div(N_GRAPHS * F_H, 256), 256, 0, stream>>>(hg, cnt);

    // ---- VAE head + decoder
    k_head<<<ceil_div(N_GRAPHS * F_L, 256), 256, 0, stream>>>(hg, Wmu, bmu, Wlv, blv, eps, out, z);
    k_dec<<<ceil_div(N_GRAPHS * F_H, 256), 256, 0, stream>>>(z, D1, db1, d1, F_L, F_H, 0);
    k_dec<<<ceil_div(N_GRAPHS * F_H, 256), 256, 0, stream>>>(d1, D2, db2, d2, F_H, F_H, 0);
    k_dec<<<ceil_div(N_GRAPHS * P_PAIRS, 256), 256, 0, stream>>>(d2, D3, db3, probs, F_H, P_PAIRS, 1);

    // ---- adjacency expansion
    k_adj<<<ceil_div(ADJ_SIZE, 256), 256, 0, stream>>>(probs, out);
}

// Round 3
// 544.209 us; speedup vs baseline: 5.0425x; 1.4268x over previous
//
#include <hip/hip_runtime.h>
#include <math.h>

#define N_NODES  20000
#define N_EDGES  320000
#define N_GRAPHS 200
#define MAXN     100
#define F_IN     128
#define F_H      256
#define F_L      64
#define P_PAIRS  4950
#define ADJ_SIZE (N_GRAPHS * MAXN * MAXN)   // 2,000,000
#define MU_OFF   ADJ_SIZE
#define LV_OFF   (ADJ_SIZE + N_GRAPHS * F_L)

static inline int ceil_div(int a, int b) { return (a + b - 1) / b; }

// ---------------------------------------------------------------- degree histogram (int)
__global__ __launch_bounds__(256) void k_deg(const int* __restrict__ dst,
                                             int* __restrict__ deg, int nE) {
    int i = blockIdx.x * blockDim.x + threadIdx.x;
    if (i < nE) atomicAdd(deg + dst[i], 1);
}

__global__ __launch_bounds__(256) void k_dinv(const int* __restrict__ deg,
                                              float* __restrict__ dinv, int n) {
    int i = blockIdx.x * blockDim.x + threadIdx.x;
    if (i < n) dinv[i] = rsqrtf((float)deg[i] + 1.0f);   // +1 self-loop
}

// ---------------------------------------------------------------- exclusive scan (single block)
__global__ __launch_bounds__(256) void k_scan(const int* __restrict__ deg,
                                              int* __restrict__ rowptr, int n) {
    __shared__ int tmp[256];
    __shared__ int carry;
    if (threadIdx.x == 0) carry = 0;
    __syncthreads();
    for (int base = 0; base < n; base += 256) {
        int i = base + threadIdx.x;
        int v = (i < n) ? deg[i] : 0;
        tmp[threadIdx.x] = v;
        __syncthreads();
        int c = carry;
        #pragma unroll
        for (int off = 1; off < 256; off <<= 1) {
            int t = (threadIdx.x >= (unsigned)off) ? tmp[threadIdx.x - off] : 0;
            __syncthreads();
            tmp[threadIdx.x] += t;
            __syncthreads();
        }
        if (i < n) rowptr[i + 1] = c + tmp[threadIdx.x];
        if (threadIdx.x == 255) carry = c + tmp[255];
        __syncthreads();
    }
    if (threadIdx.x == 0) rowptr[0] = 0;
}

// ---------------------------------------------------------------- CSR fill
__global__ __launch_bounds__(256) void k_fill(const int* __restrict__ src,
                                              const int* __restrict__ dst,
                                              const int* __restrict__ rowptr,
                                              int* __restrict__ fill,
                                              int* __restrict__ col, int nE) {
    int e = blockIdx.x * blockDim.x + threadIdx.x;
    if (e >= nE) return;
    int d = dst[e];
    int pos = rowptr[d] + atomicAdd(fill + d, 1);
    col[pos] = src[e];
}

// ---------------------------------------------------------------- templated tiled fp32 GEMM
// C[M,N] = epilogue(A[M,K] @ B[K,N]); row-major; 256 threads; TM x TN per thread.
// MODE 0: C[m][n] = acc * dinv[m]          (node GEMM, pre-scaled for gather)
// MODE 1: C[m][n] = relu(acc + bias[n])
// MODE 2: C[m][n] = sigmoid(acc + bias[n])
// Requires: K % 16 == 0; BM = 16*TM; BN = 16*TN.
template<int BM, int BN, int TM, int TN, int MODE>
__global__ __launch_bounds__(256) void k_gemm_t(const float* __restrict__ A,
                                                const float* __restrict__ B,
                                                float* __restrict__ C,
                                                int M, int N, int K,
                                                const float* __restrict__ bias,
                                                const float* __restrict__ dinv) {
    constexpr int BK = 16;
    __shared__ float As[BK][BM + 4];   // +4 keeps 16B alignment of rows
    __shared__ float Bs[BK][BN];
    const int bm = blockIdx.y * BM;
    const int bn = blockIdx.x * BN;
    const int tid = threadIdx.x;
    const int tx = tid & 15, ty = tid >> 4;
    float acc[TM][TN] = {};

    constexpr int nA4 = BM * BK / 4 / 256;   // float4 loads per thread for A
    constexpr int nB4 = BK * BN / 4 / 256;

    for (int k0 = 0; k0 < K; k0 += BK) {
        #pragma unroll
        for (int q = 0; q < nA4; ++q) {
            int lin = tid + 256 * q;          // one float4 along K
            int m  = lin >> 2;                // BK/4 = 4 groups per row
            int k4 = (lin & 3) * 4;
            int gm = bm + m;
            float4 v = make_float4(0.f, 0.f, 0.f, 0.f);
            if (gm < M) v = *(const float4*)(A + (size_t)gm * K + k0 + k4);
            As[k4 + 0][m] = v.x;
            As[k4 + 1][m] = v.y;
            As[k4 + 2][m] = v.z;
            As[k4 + 3][m] = v.w;
        }
        #pragma unroll
        for (int q = 0; q < nB4; ++q) {
            int lin = tid + 256 * q;          // one float4 along N
            int n4 = (lin % (BN / 4)) * 4;
            int kk = lin / (BN / 4);
            int gn = bn + n4;
            const float* brow = B + (size_t)(k0 + kk) * N;
            float4 v;
            if (gn + 3 < N) {
                v = *(const float4*)(brow + gn);
            } else {
                v.x = (gn + 0 < N) ? brow[gn + 0] : 0.f;
                v.y = (gn + 1 < N) ? brow[gn + 1] : 0.f;
                v.z = (gn + 2 < N) ? brow[gn + 2] : 0.f;
                v.w = (gn + 3 < N) ? brow[gn + 3] : 0.f;
            }
            *(float4*)&Bs[kk][n4] = v;
        }
        __syncthreads();
        #pragma unroll
        for (int kk = 0; kk < BK; ++kk) {
            float a[TM], b[TN];
            #pragma unroll
            for (int i = 0; i < TM; ++i) a[i] = As[kk][ty * TM + i];
            #pragma unroll
            for (int j = 0; j < TN; ++j) b[j] = Bs[kk][tx * TN + j];
            #pragma unroll
            for (int i = 0; i < TM; ++i)
                #pragma unroll
                for (int j = 0; j < TN; ++j) acc[i][j] += a[i] * b[j];
        }
        __syncthreads();
    }

    #pragma unroll
    for (int i = 0; i < TM; ++i) {
        int gm = bm + ty * TM + i;
        if (gm >= M) continue;
        float rs = 1.0f;
        if constexpr (MODE == 0) rs = dinv[gm];
        float* crow = C + (size_t)gm * N;
        #pragma unroll
        for (int j = 0; j < TN; ++j) {
            int gn = bn + tx * TN + j;
            if (gn >= N) continue;
            float s = acc[i][j];
            if constexpr (MODE == 0) {
                s *= rs;
            } else if constexpr (MODE == 1) {
                s = fmaxf(s + bias[gn], 0.0f);
            } else {
                s = 1.0f / (1.0f + expf(-(s + bias[gn])));
            }
            crow[gn] = s;
        }
    }
}

// ---------------------------------------------------------------- fused GCN aggregate
// Hs is the dinv-pre-scaled linear output: Hs[v] = dinv[v] * (x@W)[v].
// out[v] = relu(dinv[v] * (sum_{s in N(v)} Hs[s] + Hs[v]) + bias)
// one wave per node; lane covers 4 contiguous features (float4).
__global__ __launch_bounds__(256) void k_gather(const float* __restrict__ Hs,
                                                const int* __restrict__ rowptr,
                                                const int* __restrict__ col,
                                                const float* __restrict__ dinv,
                                                const float* __restrict__ bias,
                                                float* __restrict__ out) {
    int v = blockIdx.x * 4 + (threadIdx.x >> 6);
    if (v >= N_NODES) return;
    int lane = threadIdx.x & 63;
    int beg = rowptr[v], end = rowptr[v + 1];
    float4 acc = make_float4(0.f, 0.f, 0.f, 0.f);
    for (int i = beg; i < end; ++i) {
        int s = col[i];
        float4 h = ((const float4*)(Hs + (size_t)s * F_H))[lane];
        acc.x += h.x; acc.y += h.y; acc.z += h.z; acc.w += h.w;
    }
    float dv = dinv[v];
    float4 hv = ((const float4*)(Hs + (size_t)v * F_H))[lane];
    float4 b = ((const float4*)bias)[lane];
    float4 o;
    o.x = fmaxf(dv * (acc.x + hv.x) + b.x, 0.0f);
    o.y = fmaxf(dv * (acc.y + hv.y) + b.y, 0.0f);
    o.z = fmaxf(dv * (acc.z + hv.z) + b.z, 0.0f);
    o.w = fmaxf(dv * (acc.w + hv.w) + b.w, 0.0f);
    ((float4*)(out + (size_t)v * F_H))[lane] = o;
}

// ---------------------------------------------------------------- mean pool (sorted batch, no atomics)
__global__ __launch_bounds__(256) void k_pool(const float* __restrict__ h,
                                              const int* __restrict__ batch,
                                              float* __restrict__ hg) {
    int g = blockIdx.x;
    __shared__ int sBeg, sEnd;
    if (threadIdx.x == 0) {
        int lo = 0, hi = N_NODES;
        while (lo < hi) { int mid = (lo + hi) >> 1; if (batch[mid] < g) lo = mid + 1; else hi = mid; }
        sBeg = lo;
        hi = N_NODES;
        while (lo < hi) { int mid = (lo + hi) >> 1; if (batch[mid] < g + 1) lo = mid + 1; else hi = mid; }
        sEnd = lo;
    }
    __syncthreads();
    int beg = sBeg, end = sEnd;
    float acc = 0.0f;
    for (int v = beg; v < end; ++v) acc += h[(size_t)v * F_H + threadIdx.x];
    float c = fmaxf((float)(end - beg), 1.0f);
    hg[(size_t)g * F_H + threadIdx.x] = acc / c;
}

// ---------------------------------------------------------------- VAE head: mu, logvar, z
__global__ __launch_bounds__(256) void k_head(const float* __restrict__ hg,
                                              const float* __restrict__ Wmu,
                                              const float* __restrict__ bmu,
                                              const float* __restrict__ Wlv,
                                              const float* __restrict__ blv,
                                              const float* __restrict__ eps,
                                              float* __restrict__ out,
                                              float* __restrict__ z) {
    int i = blockIdx.x * blockDim.x + threadIdx.x;
    if (i >= N_GRAPHS * F_L) return;
    int g = i / F_L, l = i % F_L;
    const float* hr = hg + (size_t)g * F_H;
    float smu = 0.0f, slv = 0.0f;
    for (int k = 0; k < F_H; ++k) {
        float h = hr[k];
        smu += h * Wmu[k * F_L + l];
        slv += h * Wlv[k * F_L + l];
    }
    smu += bmu[l];
    slv += blv[l];
    out[MU_OFF + i] = smu;
    out[LV_OFF + i] = slv;
    z[i] = smu + eps[i] * expf(0.5f * slv);
}

// ---------------------------------------------------------------- adjacency expansion
__global__ __launch_bounds__(256) void k_adj(const float* __restrict__ probs,
                                             float* __restrict__ adj) {
    int i = blockIdx.x * blockDim.x + threadIdx.x;
    if (i >= ADJ_SIZE) return;
    int g = i / (MAXN * MAXN);
    int r = i % (MAXN * MAXN);
    int a = r / MAXN, b = r % MAXN;
    float v = 0.0f;
    if (a != b) {
        int lo = min(a, b), hi = max(a, b);
        int p = lo * (MAXN - 1) - (lo * (lo - 1)) / 2 + (hi - lo - 1);
        v = probs[(size_t)g * P_PAIRS + p];
    }
    adj[i] = v;
}

// ================================================================ launch
extern "C" void kernel_launch(void* const* d_in, const int* in_sizes, int n_in,
                              void* d_out, int out_size, void* d_ws, size_t ws_size,
                              hipStream_t stream) {
    const float* x    = (const float*)d_in[0];
    const int*   eidx = (const int*)d_in[1];
    const int*   batch= (const int*)d_in[2];
    const float* eps  = (const float*)d_in[3];
    const float* W1   = (const float*)d_in[4];
    const float* b1   = (const float*)d_in[5];
    const float* W2   = (const float*)d_in[6];
    const float* b2   = (const float*)d_in[7];
    const float* Wmu  = (const float*)d_in[8];
    const float* bmu  = (const float*)d_in[9];
    const float* Wlv  = (const float*)d_in[10];
    const float* blv  = (const float*)d_in[11];
    const float* D1   = (const float*)d_in[12];
    const float* db1  = (const float*)d_in[13];
    const float* D2   = (const float*)d_in[14];
    const float* db2  = (const float*)d_in[15];
    const float* D3   = (const float*)d_in[16];
    const float* db3  = (const float*)d_in[17];

    const int* src = eidx;
    const int* dst = eidx + N_EDGES;
    float* out = (float*)d_out;

    // workspace carve-up
    char* wsb = (char*)d_ws;
    size_t o = 0;
    auto carve = [&](size_t bytes) { void* p = wsb + o; o += (bytes + 255) & ~255ull; return p; };
    int*   deg    = (int*)  carve(N_NODES * sizeof(int));
    int*   fill   = (int*)  carve(N_NODES * sizeof(int));
    int*   rowptr = (int*)  carve((N_NODES + 1) * sizeof(int));
    int*   col    = (int*)  carve(N_EDGES * sizeof(int));
    float* dinv   = (float*)carve(N_NODES * sizeof(float));
    float* bufA   = (float*)carve((size_t)N_NODES * F_H * sizeof(float));
    float* bufB   = (float*)carve((size_t)N_NODES * F_H * sizeof(float));
    float* hg     = (float*)carve((size_t)N_GRAPHS * F_H * sizeof(float));
    float* z      = (float*)carve((size_t)N_GRAPHS * F_L * sizeof(float));
    float* d1     = (float*)carve((size_t)N_GRAPHS * F_H * sizeof(float));
    float* d2     = (float*)carve((size_t)N_GRAPHS * F_H * sizeof(float));
    float* probs  = (float*)carve((size_t)N_GRAPHS * P_PAIRS * sizeof(float));

    // ---- CSR build (shared by both layers)
    hipMemsetAsync(deg, 0, N_NODES * sizeof(int), stream);
    hipMemsetAsync(fill, 0, N_NODES * sizeof(int), stream);
    k_deg<<<ceil_div(N_EDGES, 256), 256, 0, stream>>>(dst, deg, N_EDGES);
    k_scan<<<1, 256, 0, stream>>>(deg, rowptr, N_NODES);
    k_dinv<<<ceil_div(N_NODES, 256), 256, 0, stream>>>(deg, dinv, N_NODES);
    k_fill<<<ceil_div(N_EDGES, 256), 256, 0, stream>>>(src, dst, rowptr, fill, col, N_EDGES);

    // ---- GCN layer 1: GEMM (dinv-scaled epilogue) + fused aggregate
    {
        dim3 grid(ceil_div(F_H, 128), ceil_div(N_NODES, 128));
        k_gemm_t<128, 128, 8, 8, 0><<<grid, 256, 0, stream>>>(
            x, W1, bufA, N_NODES, F_H, F_IN, nullptr, dinv);
    }
    k_gather<<<ceil_div(N_NODES, 4), 256, 0, stream>>>(bufA, rowptr, col, dinv, b1, bufB);

    // ---- GCN layer 2
    {
        dim3 grid(ceil_div(F_H, 128), ceil_div(N_NODES, 128));
        k_gemm_t<128, 128, 8, 8, 0><<<grid, 256, 0, stream>>>(
            bufB, W2, bufA, N_NODES, F_H, F_H, nullptr, dinv);
    }
    k_gather<<<ceil_div(N_NODES, 4), 256, 0, stream>>>(bufA, rowptr, col, dinv, b2, bufB);

    // ---- global mean pool (sorted batch, atomic-free)
    k_pool<<<N_GRAPHS, 256, 0, stream>>>(bufB, batch, hg);

    // ---- VAE head + decoder
    k_head<<<ceil_div(N_GRAPHS * F_L, 256), 256, 0, stream>>>(hg, Wmu, bmu, Wlv, blv, eps, out, z);
    {
        dim3 grid(ceil_div(F_H, 64), ceil_div(N_GRAPHS, 64));
        k_gemm_t<64, 64, 4, 4, 1><<<grid, 256, 0, stream>>>(
            z, D1, d1, N_GRAPHS, F_H, F_L, db1, nullptr);
        k_gemm_t<64, 64, 4, 4, 1><<<grid, 256, 0, stream>>>(
            d1, D2, d2, N_GRAPHS, F_H, F_H, db2, nullptr);
    }
    {
        dim3 grid(ceil_div(P_PAIRS, 64), ceil_div(N_GRAPHS, 64));
        k_gemm_t<64, 64, 4, 4, 2><<<grid, 256, 0, stream>>>(
            d2, D3, probs, N_GRAPHS, P_PAIRS, F_H, db3, nullptr);
    }

    // ---- adjacency expansion
    k_adj<<<ceil_div(ADJ_SIZE, 256), 256, 0, stream>>>(probs, out);
}

// Round 4
// 452.903 us; speedup vs baseline: 6.0590x; 1.2016x over previous
//
#include <hip/hip_runtime.h>
#include <math.h>

#define N_NODES  20000
#define N_EDGES  320000
#define N_GRAPHS 200
#define MAXN     100
#define F_IN     128
#define F_H      256
#define F_L      64
#define P_PAIRS  4950
#define ADJ_SIZE (N_GRAPHS * MAXN * MAXN)   // 2,000,000
#define MU_OFF   ADJ_SIZE
#define LV_OFF   (ADJ_SIZE + N_GRAPHS * F_L)

#define SCAN_NB  ((N_NODES + 255) / 256)    // 79 blocks

static inline int ceil_div(int a, int b) { return (a + b - 1) / b; }

// ---------------------------------------------------------------- degree histogram (int)
__global__ __launch_bounds__(256) void k_deg(const int* __restrict__ dst,
                                             int* __restrict__ deg, int nE) {
    int i = blockIdx.x * blockDim.x + threadIdx.x;
    if (i < nE) atomicAdd(deg + dst[i], 1);
}

__global__ __launch_bounds__(256) void k_dinv(const int* __restrict__ deg,
                                              float* __restrict__ dinv, int n) {
    int i = blockIdx.x * blockDim.x + threadIdx.x;
    if (i < n) dinv[i] = rsqrtf((float)deg[i] + 1.0f);   // +1 self-loop
}

// ---------------------------------------------------------------- 3-phase parallel scan
// Phase A: per-block inclusive scan; rowptr[i+1] = local inclusive; bsum[b] = block total
__global__ __launch_bounds__(256) void k_scan_local(const int* __restrict__ deg,
                                                    int* __restrict__ rowptr,
                                                    int* __restrict__ bsum, int n) {
    __shared__ int tmp[256];
    int i = blockIdx.x * 256 + threadIdx.x;
    int v = (i < n) ? deg[i] : 0;
    tmp[threadIdx.x] = v;
    __syncthreads();
    #pragma unroll
    for (int off = 1; off < 256; off <<= 1) {
        int t = (threadIdx.x >= (unsigned)off) ? tmp[threadIdx.x - off] : 0;
        __syncthreads();
        tmp[threadIdx.x] += t;
        __syncthreads();
    }
    if (i < n) rowptr[i + 1] = tmp[threadIdx.x];
    if (threadIdx.x == 255) bsum[blockIdx.x] = tmp[255];
}

// Phase B: single-block exclusive scan of the block sums (nb <= 128)
__global__ __launch_bounds__(128) void k_scan_bsum(int* __restrict__ bsum, int nb) {
    __shared__ int tmp[128];
    int v = (threadIdx.x < nb) ? bsum[threadIdx.x] : 0;
    tmp[threadIdx.x] = v;
    __syncthreads();
    #pragma unroll
    for (int off = 1; off < 128; off <<= 1) {
        int t = (threadIdx.x >= (unsigned)off) ? tmp[threadIdx.x - off] : 0;
        __syncthreads();
        tmp[threadIdx.x] += t;
        __syncthreads();
    }
    if (threadIdx.x < nb) bsum[threadIdx.x] = tmp[threadIdx.x] - v;  // exclusive
}

// Phase C: add block offsets
__global__ __launch_bounds__(256) void k_scan_add(int* __restrict__ rowptr,
                                                  const int* __restrict__ bsum, int n) {
    int i = blockIdx.x * 256 + threadIdx.x;
    if (i < n) rowptr[i + 1] += bsum[blockIdx.x];
    if (blockIdx.x == 0 && threadIdx.x == 0) rowptr[0] = 0;
}

// ---------------------------------------------------------------- CSR fill
__global__ __launch_bounds__(256) void k_fill(const int* __restrict__ src,
                                              const int* __restrict__ dst,
                                              const int* __restrict__ rowptr,
                                              int* __restrict__ fill,
                                              int* __restrict__ col, int nE) {
    int e = blockIdx.x * blockDim.x + threadIdx.x;
    if (e >= nE) return;
    int d = dst[e];
    int pos = rowptr[d] + atomicAdd(fill + d, 1);
    col[pos] = src[e];
}

// ---------------------------------------------------------------- templated tiled fp32 GEMM
// C[M,N] = epilogue(A[M,K] @ B[K,N]); row-major; 256 threads; TM x TN per thread.
// MODE 0: C[m][n] = acc * dinv[m]          (node GEMM, pre-scaled for gather)
// MODE 1: C[m][n] = relu(acc + bias[n])
// MODE 2: C[m][n] = sigmoid(acc + bias[n])
// Requires: K % 16 == 0; BM = 16*TM; BN = 16*TN.
template<int BM, int BN, int TM, int TN, int MODE>
__global__ __launch_bounds__(256) void k_gemm_t(const float* __restrict__ A,
                                                const float* __restrict__ B,
                                                float* __restrict__ C,
                                                int M, int N, int K,
                                                const float* __restrict__ bias,
                                                const float* __restrict__ dinv) {
    constexpr int BK = 16;
    __shared__ float As[BK][BM + 4];   // +4 keeps 16B alignment of rows
    __shared__ float Bs[BK][BN];
    const int bm = blockIdx.y * BM;
    const int bn = blockIdx.x * BN;
    const int tid = threadIdx.x;
    const int tx = tid & 15, ty = tid >> 4;
    float acc[TM][TN] = {};

    constexpr int nA4 = BM * BK / 4 / 256;   // float4 loads per thread for A
    constexpr int nB4 = BK * BN / 4 / 256;

    for (int k0 = 0; k0 < K; k0 += BK) {
        #pragma unroll
        for (int q = 0; q < nA4; ++q) {
            int lin = tid + 256 * q;          // one float4 along K
            int m  = lin >> 2;                // BK/4 = 4 groups per row
            int k4 = (lin & 3) * 4;
            int gm = bm + m;
            float4 v = make_float4(0.f, 0.f, 0.f, 0.f);
            if (gm < M) v = *(const float4*)(A + (size_t)gm * K + k0 + k4);
            As[k4 + 0][m] = v.x;
            As[k4 + 1][m] = v.y;
            As[k4 + 2][m] = v.z;
            As[k4 + 3][m] = v.w;
        }
        #pragma unroll
        for (int q = 0; q < nB4; ++q) {
            int lin = tid + 256 * q;          // one float4 along N
            int n4 = (lin % (BN / 4)) * 4;
            int kk = lin / (BN / 4);
            int gn = bn + n4;
            const float* brow = B + (size_t)(k0 + kk) * N;
            float4 v;
            if (gn + 3 < N) {
                v = *(const float4*)(brow + gn);
            } else {
                v.x = (gn + 0 < N) ? brow[gn + 0] : 0.f;
                v.y = (gn + 1 < N) ? brow[gn + 1] : 0.f;
                v.z = (gn + 2 < N) ? brow[gn + 2] : 0.f;
                v.w = (gn + 3 < N) ? brow[gn + 3] : 0.f;
            }
            *(float4*)&Bs[kk][n4] = v;
        }
        __syncthreads();
        #pragma unroll
        for (int kk = 0; kk < BK; ++kk) {
            float a[TM], b[TN];
            #pragma unroll
            for (int i = 0; i < TM; ++i) a[i] = As[kk][ty * TM + i];
            #pragma unroll
            for (int j = 0; j < TN; ++j) b[j] = Bs[kk][tx * TN + j];
            #pragma unroll
            for (int i = 0; i < TM; ++i)
                #pragma unroll
                for (int j = 0; j < TN; ++j) acc[i][j] += a[i] * b[j];
        }
        __syncthreads();
    }

    #pragma unroll
    for (int i = 0; i < TM; ++i) {
        int gm = bm + ty * TM + i;
        if (gm >= M) continue;
        float rs = 1.0f;
        if constexpr (MODE == 0) rs = dinv[gm];
        float* crow = C + (size_t)gm * N;
        #pragma unroll
        for (int j = 0; j < TN; ++j) {
            int gn = bn + tx * TN + j;
            if (gn >= N) continue;
            float s = acc[i][j];
            if constexpr (MODE == 0) {
                s *= rs;
            } else if constexpr (MODE == 1) {
                s = fmaxf(s + bias[gn], 0.0f);
            } else {
                s = 1.0f / (1.0f + expf(-(s + bias[gn])));
            }
            crow[gn] = s;
        }
    }
}

// ---------------------------------------------------------------- fused GCN aggregate
// Hs is the dinv-pre-scaled linear output: Hs[v] = dinv[v] * (x@W)[v].
// out[v] = relu(dinv[v] * (sum_{s in N(v)} Hs[s] + Hs[v]) + bias)
// one wave per node; lane covers 4 contiguous features (float4).
// Unrolled by 4: 4 independent row reads in flight per wave.
__global__ __launch_bounds__(256) void k_gather(const float* __restrict__ Hs,
                                                const int* __restrict__ rowptr,
                                                const int* __restrict__ col,
                                                const float* __restrict__ dinv,
                                                const float* __restrict__ bias,
                                                float* __restrict__ out) {
    int v = blockIdx.x * 4 + (threadIdx.x >> 6);
    if (v >= N_NODES) return;
    int lane = threadIdx.x & 63;
    int beg = rowptr[v], end = rowptr[v + 1];
    float4 a0 = make_float4(0.f, 0.f, 0.f, 0.f);
    float4 a1 = make_float4(0.f, 0.f, 0.f, 0.f);
    int i = beg;
    for (; i + 4 <= end; i += 4) {
        int s0 = col[i + 0], s1 = col[i + 1], s2 = col[i + 2], s3 = col[i + 3];
        float4 h0 = ((const float4*)(Hs + (size_t)s0 * F_H))[lane];
        float4 h1 = ((const float4*)(Hs + (size_t)s1 * F_H))[lane];
        float4 h2 = ((const float4*)(Hs + (size_t)s2 * F_H))[lane];
        float4 h3 = ((const float4*)(Hs + (size_t)s3 * F_H))[lane];
        a0.x += h0.x + h1.x; a0.y += h0.y + h1.y;
        a0.z += h0.z + h1.z; a0.w += h0.w + h1.w;
        a1.x += h2.x + h3.x; a1.y += h2.y + h3.y;
        a1.z += h2.z + h3.z; a1.w += h2.w + h3.w;
    }
    for (; i < end; ++i) {
        int s = col[i];
        float4 h = ((const float4*)(Hs + (size_t)s * F_H))[lane];
        a0.x += h.x; a0.y += h.y; a0.z += h.z; a0.w += h.w;
    }
    float dv = dinv[v];
    float4 hv = ((const float4*)(Hs + (size_t)v * F_H))[lane];
    float4 b = ((const float4*)bias)[lane];
    float4 o;
    o.x = fmaxf(dv * (a0.x + a1.x + hv.x) + b.x, 0.0f);
    o.y = fmaxf(dv * (a0.y + a1.y + hv.y) + b.y, 0.0f);
    o.z = fmaxf(dv * (a0.z + a1.z + hv.z) + b.z, 0.0f);
    o.w = fmaxf(dv * (a0.w + a1.w + hv.w) + b.w, 0.0f);
    ((float4*)(out + (size_t)v * F_H))[lane] = o;
}

// ---------------------------------------------------------------- mean pool (sorted batch, no atomics)
__global__ __launch_bounds__(256) void k_pool(const float* __restrict__ h,
                                              const int* __restrict__ batch,
                                              float* __restrict__ hg) {
    int g = blockIdx.x;
    __shared__ int sBeg, sEnd;
    if (threadIdx.x == 0) {
        int lo = 0, hi = N_NODES;
        while (lo < hi) { int mid = (lo + hi) >> 1; if (batch[mid] < g) lo = mid + 1; else hi = mid; }
        sBeg = lo;
        hi = N_NODES;
        while (lo < hi) { int mid = (lo + hi) >> 1; if (batch[mid] < g + 1) lo = mid + 1; else hi = mid; }
        sEnd = lo;
    }
    __syncthreads();
    int beg = sBeg, end = sEnd;
    float acc = 0.0f;
    for (int v = beg; v < end; ++v) acc += h[(size_t)v * F_H + threadIdx.x];
    float c = fmaxf((float)(end - beg), 1.0f);
    hg[(size_t)g * F_H + threadIdx.x] = acc / c;
}

// ---------------------------------------------------------------- VAE head: mu, logvar, z
__global__ __launch_bounds__(256) void k_head(const float* __restrict__ hg,
                                              const float* __restrict__ Wmu,
                                              const float* __restrict__ bmu,
                                              const float* __restrict__ Wlv,
                                              const float* __restrict__ blv,
                                              const float* __restrict__ eps,
                                              float* __restrict__ out,
                                              float* __restrict__ z) {
    int i = blockIdx.x * blockDim.x + threadIdx.x;
    if (i >= N_GRAPHS * F_L) return;
    int g = i / F_L, l = i % F_L;
    const float* hr = hg + (size_t)g * F_H;
    float smu = 0.0f, slv = 0.0f;
    for (int k = 0; k < F_H; ++k) {
        float h = hr[k];
        smu += h * Wmu[k * F_L + l];
        slv += h * Wlv[k * F_L + l];
    }
    smu += bmu[l];
    slv += blv[l];
    out[MU_OFF + i] = smu;
    out[LV_OFF + i] = slv;
    z[i] = smu + eps[i] * expf(0.5f * slv);
}

// ---------------------------------------------------------------- adjacency expansion
__global__ __launch_bounds__(256) void k_adj(const float* __restrict__ probs,
                                             float* __restrict__ adj) {
    int i = blockIdx.x * blockDim.x + threadIdx.x;
    if (i >= ADJ_SIZE) return;
    int g = i / (MAXN * MAXN);
    int r = i % (MAXN * MAXN);
    int a = r / MAXN, b = r % MAXN;
    float v = 0.0f;
    if (a != b) {
        int lo = min(a, b), hi = max(a, b);
        int p = lo * (MAXN - 1) - (lo * (lo - 1)) / 2 + (hi - lo - 1);
        v = probs[(size_t)g * P_PAIRS + p];
    }
    adj[i] = v;
}

// ================================================================ launch
extern "C" void kernel_launch(void* const* d_in, const int* in_sizes, int n_in,
                              void* d_out, int out_size, void* d_ws, size_t ws_size,
                              hipStream_t stream) {
    const float* x    = (const float*)d_in[0];
    const int*   eidx = (const int*)d_in[1];
    const int*   batch= (const int*)d_in[2];
    const float* eps  = (const float*)d_in[3];
    const float* W1   = (const float*)d_in[4];
    const float* b1   = (const float*)d_in[5];
    const float* W2   = (const float*)d_in[6];
    const float* b2   = (const float*)d_in[7];
    const float* Wmu  = (const float*)d_in[8];
    const float* bmu  = (const float*)d_in[9];
    const float* Wlv  = (const float*)d_in[10];
    const float* blv  = (const float*)d_in[11];
    const float* D1   = (const float*)d_in[12];
    const float* db1  = (const float*)d_in[13];
    const float* D2   = (const float*)d_in[14];
    const float* db2  = (const float*)d_in[15];
    const float* D3   = (const float*)d_in[16];
    const float* db3  = (const float*)d_in[17];

    const int* src = eidx;
    const int* dst = eidx + N_EDGES;
    float* out = (float*)d_out;

    // workspace carve-up
    char* wsb = (char*)d_ws;
    size_t o = 0;
    auto carve = [&](size_t bytes) { void* p = wsb + o; o += (bytes + 255) & ~255ull; return p; };
    int*   deg    = (int*)  carve(N_NODES * sizeof(int));
    int*   fill   = (int*)  carve(N_NODES * sizeof(int));
    int*   rowptr = (int*)  carve((N_NODES + 1) * sizeof(int));
    int*   bsum   = (int*)  carve(128 * sizeof(int));
    int*   col    = (int*)  carve(N_EDGES * sizeof(int));
    float* dinv   = (float*)carve(N_NODES * sizeof(float));
    float* bufA   = (float*)carve((size_t)N_NODES * F_H * sizeof(float));
    float* bufB   = (float*)carve((size_t)N_NODES * F_H * sizeof(float));
    float* hg     = (float*)carve((size_t)N_GRAPHS * F_H * sizeof(float));
    float* z      = (float*)carve((size_t)N_GRAPHS * F_L * sizeof(float));
    float* d1     = (float*)carve((size_t)N_GRAPHS * F_H * sizeof(float));
    float* d2     = (float*)carve((size_t)N_GRAPHS * F_H * sizeof(float));
    float* probs  = (float*)carve((size_t)N_GRAPHS * P_PAIRS * sizeof(float));

    // ---- CSR build (shared by both layers)
    hipMemsetAsync(deg, 0, N_NODES * sizeof(int), stream);
    hipMemsetAsync(fill, 0, N_NODES * sizeof(int), stream);
    k_deg<<<ceil_div(N_EDGES, 256), 256, 0, stream>>>(dst, deg, N_EDGES);
    k_scan_local<<<SCAN_NB, 256, 0, stream>>>(deg, rowptr, bsum, N_NODES);
    k_scan_bsum<<<1, 128, 0, stream>>>(bsum, SCAN_NB);
    k_scan_add<<<SCAN_NB, 256, 0, stream>>>(rowptr, bsum, N_NODES);
    k_dinv<<<ceil_div(N_NODES, 256), 256, 0, stream>>>(deg, dinv, N_NODES);
    k_fill<<<ceil_div(N_EDGES, 256), 256, 0, stream>>>(src, dst, rowptr, fill, col, N_EDGES);

    // ---- GCN layer 1: GEMM (dinv-scaled epilogue) + fused aggregate
    {
        dim3 grid(ceil_div(F_H, 128), ceil_div(N_NODES, 128));
        k_gemm_t<128, 128, 8, 8, 0><<<grid, 256, 0, stream>>>(
            x, W1, bufA, N_NODES, F_H, F_IN, nullptr, dinv);
    }
    k_gather<<<ceil_div(N_NODES, 4), 256, 0, stream>>>(bufA, rowptr, col, dinv, b1, bufB);

    // ---- GCN layer 2
    {
        dim3 grid(ceil_div(F_H, 128), ceil_div(N_NODES, 128));
        k_gemm_t<128, 128, 8, 8, 0><<<grid, 256, 0, stream>>>(
            bufB, W2, bufA, N_NODES, F_H, F_H, nullptr, dinv);
    }
    k_gather<<<ceil_div(N_NODES, 4), 256, 0, stream>>>(bufA, rowptr, col, dinv, b2, bufB);

    // ---- global mean pool (sorted batch, atomic-free)
    k_pool<<<N_GRAPHS, 256, 0, stream>>>(bufB, batch, hg);

    // ---- VAE head + decoder
    k_head<<<ceil_div(N_GRAPHS * F_L, 256), 256, 0, stream>>>(hg, Wmu, bmu, Wlv, blv, eps, out, z);
    {
        dim3 grid(ceil_div(F_H, 64), ceil_div(N_GRAPHS, 64));
        k_gemm_t<64, 64, 4, 4, 1><<<grid, 256, 0, stream>>>(
            z, D1, d1, N_GRAPHS, F_H, F_L, db1, nullptr);
        k_gemm_t<64, 64, 4, 4, 1><<<grid, 256, 0, stream>>>(
            d1, D2, d2, N_GRAPHS, F_H, F_H, db2, nullptr);
    }
    {
        dim3 grid(ceil_div(P_PAIRS, 64), ceil_div(N_GRAPHS, 64));
        k_gemm_t<64, 64, 4, 4, 2><<<grid, 256, 0, stream>>>(
            d2, D3, probs, N_GRAPHS, P_PAIRS, F_H, db3, nullptr);
    }

    // ---- adjacency expansion
    k_adj<<<ceil_div(ADJ_SIZE, 256), 256, 0, stream>>>(probs, out);
}

// Round 5
// 374.609 us; speedup vs baseline: 7.3254x; 1.2090x over previous
//
#include <hip/hip_runtime.h>
#include <math.h>

#define N_NODES  20000
#define N_EDGES  320000
#define N_GRAPHS 200
#define MAXN     100
#define F_IN     128
#define F_H      256
#define F_L      64
#define P_PAIRS  4950
#define ADJ_SIZE (N_GRAPHS * MAXN * MAXN)   // 2,000,000
#define MU_OFF   ADJ_SIZE
#define LV_OFF   (ADJ_SIZE + N_GRAPHS * F_L)

#define SCAN_NB  ((N_NODES + 255) / 256)    // 79 blocks

static inline int ceil_div(int a, int b) { return (a + b - 1) / b; }

typedef __attribute__((ext_vector_type(8))) short bf16x8;   // 4 VGPRs
typedef __attribute__((ext_vector_type(4))) float f32x4;    // MFMA acc

// fp32 -> bf16 round-to-nearest-even
static __device__ inline unsigned short f2bf(float f) {
    union { float f; unsigned u; } v; v.f = f;
    unsigned r = (v.u + 0x7FFFu + ((v.u >> 16) & 1u)) >> 16;
    return (unsigned short)r;
}

// ---------------------------------------------------------------- degree histogram (int)
__global__ __launch_bounds__(256) void k_deg(const int* __restrict__ dst,
                                             int* __restrict__ deg, int nE) {
    int i = blockIdx.x * blockDim.x + threadIdx.x;
    if (i < nE) atomicAdd(deg + dst[i], 1);
}

__global__ __launch_bounds__(256) void k_dinv(const int* __restrict__ deg,
                                              float* __restrict__ dinv, int n) {
    int i = blockIdx.x * blockDim.x + threadIdx.x;
    if (i < n) dinv[i] = rsqrtf((float)deg[i] + 1.0f);   // +1 self-loop
}

// ---------------------------------------------------------------- 3-phase parallel scan
__global__ __launch_bounds__(256) void k_scan_local(const int* __restrict__ deg,
                                                    int* __restrict__ rowptr,
                                                    int* __restrict__ bsum, int n) {
    __shared__ int tmp[256];
    int i = blockIdx.x * 256 + threadIdx.x;
    int v = (i < n) ? deg[i] : 0;
    tmp[threadIdx.x] = v;
    __syncthreads();
    #pragma unroll
    for (int off = 1; off < 256; off <<= 1) {
        int t = (threadIdx.x >= (unsigned)off) ? tmp[threadIdx.x - off] : 0;
        __syncthreads();
        tmp[threadIdx.x] += t;
        __syncthreads();
    }
    if (i < n) rowptr[i + 1] = tmp[threadIdx.x];
    if (threadIdx.x == 255) bsum[blockIdx.x] = tmp[255];
}

__global__ __launch_bounds__(128) void k_scan_bsum(int* __restrict__ bsum, int nb) {
    __shared__ int tmp[128];
    int v = (threadIdx.x < nb) ? bsum[threadIdx.x] : 0;
    tmp[threadIdx.x] = v;
    __syncthreads();
    #pragma unroll
    for (int off = 1; off < 128; off <<= 1) {
        int t = (threadIdx.x >= (unsigned)off) ? tmp[threadIdx.x - off] : 0;
        __syncthreads();
        tmp[threadIdx.x] += t;
        __syncthreads();
    }
    if (threadIdx.x < nb) bsum[threadIdx.x] = tmp[threadIdx.x] - v;  // exclusive
}

__global__ __launch_bounds__(256) void k_scan_add(int* __restrict__ rowptr,
                                                  const int* __restrict__ bsum, int n) {
    int i = blockIdx.x * 256 + threadIdx.x;
    if (i < n) rowptr[i + 1] += bsum[blockIdx.x];
    if (blockIdx.x == 0 && threadIdx.x == 0) rowptr[0] = 0;
}

// ---------------------------------------------------------------- CSR fill
__global__ __launch_bounds__(256) void k_fill(const int* __restrict__ src,
                                              const int* __restrict__ dst,
                                              const int* __restrict__ rowptr,
                                              int* __restrict__ fill,
                                              int* __restrict__ col, int nE) {
    int e = blockIdx.x * blockDim.x + threadIdx.x;
    if (e >= nE) return;
    int d = dst[e];
    int pos = rowptr[d] + atomicAdd(fill + d, 1);
    col[pos] = src[e];
}

// ---------------------------------------------------------------- fp32 -> bf16 cast (vec4)
__global__ __launch_bounds__(256) void k_cvt(const float* __restrict__ in,
                                             unsigned short* __restrict__ out, int n4) {
    int i = blockIdx.x * blockDim.x + threadIdx.x;
    if (i >= n4) return;
    float4 v = ((const float4*)in)[i];
    ushort4 o;
    o.x = f2bf(v.x); o.y = f2bf(v.y); o.z = f2bf(v.z); o.w = f2bf(v.w);
    ((ushort4*)out)[i] = o;
}

// ---------------------------------------------------------------- weight prepack into B-fragment order
// Bp[((kt*NT + nt)*64 + lane)*8 + j] = bf16(W[kt*32 + (lane>>4)*8 + j][nt*16 + (lane&15)])
__global__ __launch_bounds__(256) void k_prepack(const float* __restrict__ W,
                                                 unsigned short* __restrict__ Bp,
                                                 int K, int N) {
    int tid = blockIdx.x * 256 + threadIdx.x;
    if (tid >= K * N) return;
    int j    = tid & 7;
    int lane = (tid >> 3) & 63;
    int t    = tid >> 9;
    int NT   = N >> 4;
    int nt   = t % NT;
    int kt   = t / NT;
    int k = kt * 32 + (lane >> 4) * 8 + j;
    int n = nt * 16 + (lane & 15);
    Bp[tid] = f2bf(W[(size_t)k * N + n]);
}

// ---------------------------------------------------------------- MFMA bf16 node GEMM
// C[M,N] = dinv[m] * (A[M,K]bf16 @ W[K,N]); LDS-free, barrier-free.
// Block: 256 thr = 4 waves; block tile 128 rows x 64 cols; wave tile 32x64.
// A-frag: direct b128 global load (8 contiguous bf16 along K).
// B-frag: prepacked Bp, one coalesced b128 per (kt, ntile) per lane (L2-resident).
template<int KDIM>
__global__ __launch_bounds__(256) void k_gemm_mfma(const unsigned short* __restrict__ A,
                                                   const unsigned short* __restrict__ Bp,
                                                   float* __restrict__ C,
                                                   const float* __restrict__ dinv,
                                                   int M, int N) {
    constexpr int KT = KDIM / 32;
    const int NT   = N >> 4;
    const int lane = threadIdx.x & 63;
    const int wave = threadIdx.x >> 6;
    const int bm   = blockIdx.y * 128 + wave * 32;
    const int ng0  = blockIdx.x * 4;            // base n-tile (4 tiles = 64 cols)
    const int quad = lane >> 4;
    const int l15  = lane & 15;

    int m0 = bm + l15;            // A-frag row, tile 0 (lane&15 indexes m for A operand)
    int m1 = m0 + 16;             // tile 1
    int m0c = min(m0, M - 1), m1c = min(m1, M - 1);

    f32x4 acc[2][4];
    #pragma unroll
    for (int i = 0; i < 2; ++i)
        #pragma unroll
        for (int nt = 0; nt < 4; ++nt) acc[i][nt] = (f32x4){0.f, 0.f, 0.f, 0.f};

    #pragma unroll
    for (int kt = 0; kt < KT; ++kt) {
        bf16x8 a0 = *(const bf16x8*)(A + (size_t)m0c * KDIM + kt * 32 + quad * 8);
        bf16x8 a1 = *(const bf16x8*)(A + (size_t)m1c * KDIM + kt * 32 + quad * 8);
        #pragma unroll
        for (int nt = 0; nt < 4; ++nt) {
            bf16x8 b = *(const bf16x8*)(Bp + (((size_t)kt * NT + ng0 + nt) * 64 + lane) * 8);
            acc[0][nt] = __builtin_amdgcn_mfma_f32_16x16x32_bf16(a0, b, acc[0][nt], 0, 0, 0);
            acc[1][nt] = __builtin_amdgcn_mfma_f32_16x16x32_bf16(a1, b, acc[1][nt], 0, 0, 0);
        }
    }

    // C/D layout: col = lane&15, row = quad*4 + reg  (dtype-independent, m89-verified)
    #pragma unroll
    for (int i = 0; i < 2; ++i) {
        #pragma unroll
        for (int r = 0; r < 4; ++r) {
            int gm = bm + i * 16 + quad * 4 + r;
            if (gm < M) {
                float dv = dinv[gm];
                float* crow = C + (size_t)gm * N + (ng0 << 4);
                #pragma unroll
                for (int nt = 0; nt < 4; ++nt)
                    crow[nt * 16 + l15] = acc[i][nt][r] * dv;
            }
        }
    }
}

// ---------------------------------------------------------------- templated tiled fp32 GEMM (decoder)
// MODE 1: relu(acc + bias[n]) ; MODE 2: sigmoid(acc + bias[n])
template<int BM, int BN, int TM, int TN, int MODE>
__global__ __launch_bounds__(256) void k_gemm_t(const float* __restrict__ A,
                                                const float* __restrict__ B,
                                                float* __restrict__ C,
                                                int M, int N, int K,
                                                const float* __restrict__ bias) {
    constexpr int BK = 16;
    __shared__ float As[BK][BM + 4];
    __shared__ float Bs[BK][BN];
    const int bm = blockIdx.y * BM;
    const int bn = blockIdx.x * BN;
    const int tid = threadIdx.x;
    const int tx = tid & 15, ty = tid >> 4;
    float acc[TM][TN] = {};

    constexpr int nA4 = BM * BK / 4 / 256;
    constexpr int nB4 = BK * BN / 4 / 256;

    for (int k0 = 0; k0 < K; k0 += BK) {
        #pragma unroll
        for (int q = 0; q < nA4; ++q) {
            int lin = tid + 256 * q;
            int m  = lin >> 2;
            int k4 = (lin & 3) * 4;
            int gm = bm + m;
            float4 v = make_float4(0.f, 0.f, 0.f, 0.f);
            if (gm < M) v = *(const float4*)(A + (size_t)gm * K + k0 + k4);
            As[k4 + 0][m] = v.x;
            As[k4 + 1][m] = v.y;
            As[k4 + 2][m] = v.z;
            As[k4 + 3][m] = v.w;
        }
        #pragma unroll
        for (int q = 0; q < nB4; ++q) {
            int lin = tid + 256 * q;
            int n4 = (lin % (BN / 4)) * 4;
            int kk = lin / (BN / 4);
            int gn = bn + n4;
            const float* brow = B + (size_t)(k0 + kk) * N;
            float4 v;
            if (gn + 3 < N) {
                v = *(const float4*)(brow + gn);
            } else {
                v.x = (gn + 0 < N) ? brow[gn + 0] : 0.f;
                v.y = (gn + 1 < N) ? brow[gn + 1] : 0.f;
                v.z = (gn + 2 < N) ? brow[gn + 2] : 0.f;
                v.w = (gn + 3 < N) ? brow[gn + 3] : 0.f;
            }
            *(float4*)&Bs[kk][n4] = v;
        }
        __syncthreads();
        #pragma unroll
        for (int kk = 0; kk < BK; ++kk) {
            float a[TM], b[TN];
            #pragma unroll
            for (int i = 0; i < TM; ++i) a[i] = As[kk][ty * TM + i];
            #pragma unroll
            for (int j = 0; j < TN; ++j) b[j] = Bs[kk][tx * TN + j];
            #pragma unroll
            for (int i = 0; i < TM; ++i)
                #pragma unroll
                for (int j = 0; j < TN; ++j) acc[i][j] += a[i] * b[j];
        }
        __syncthreads();
    }

    #pragma unroll
    for (int i = 0; i < TM; ++i) {
        int gm = bm + ty * TM + i;
        if (gm >= M) continue;
        float* crow = C + (size_t)gm * N;
        #pragma unroll
        for (int j = 0; j < TN; ++j) {
            int gn = bn + tx * TN + j;
            if (gn >= N) continue;
            float s = acc[i][j];
            if constexpr (MODE == 1) {
                s = fmaxf(s + bias[gn], 0.0f);
            } else {
                s = 1.0f / (1.0f + expf(-(s + bias[gn])));
            }
            crow[gn] = s;
        }
    }
}

// ---------------------------------------------------------------- fused GCN aggregate
// Hs[v] = dinv[v] * (A@W)[v] (fp32). out[v] = relu(dinv[v]*(sum Hs[s] + Hs[v]) + bias)
// BF16OUT: write bf16 (ushort4) rows for the next MFMA GEMM's A operand.
template<bool BF16OUT>
__global__ __launch_bounds__(256) void k_gather(const float* __restrict__ Hs,
                                                const int* __restrict__ rowptr,
                                                const int* __restrict__ col,
                                                const float* __restrict__ dinv,
                                                const float* __restrict__ bias,
                                                void* __restrict__ outp) {
    int v = blockIdx.x * 4 + (threadIdx.x >> 6);
    if (v >= N_NODES) return;
    int lane = threadIdx.x & 63;
    int beg = rowptr[v], end = rowptr[v + 1];
    float4 a0 = make_float4(0.f, 0.f, 0.f, 0.f);
    float4 a1 = make_float4(0.f, 0.f, 0.f, 0.f);
    int i = beg;
    for (; i + 4 <= end; i += 4) {
        int s0 = col[i + 0], s1 = col[i + 1], s2 = col[i + 2], s3 = col[i + 3];
        float4 h0 = ((const float4*)(Hs + (size_t)s0 * F_H))[lane];
        float4 h1 = ((const float4*)(Hs + (size_t)s1 * F_H))[lane];
        float4 h2 = ((const float4*)(Hs + (size_t)s2 * F_H))[lane];
        float4 h3 = ((const float4*)(Hs + (size_t)s3 * F_H))[lane];
        a0.x += h0.x + h1.x; a0.y += h0.y + h1.y;
        a0.z += h0.z + h1.z; a0.w += h0.w + h1.w;
        a1.x += h2.x + h3.x; a1.y += h2.y + h3.y;
        a1.z += h2.z + h3.z; a1.w += h2.w + h3.w;
    }
    for (; i < end; ++i) {
        int s = col[i];
        float4 h = ((const float4*)(Hs + (size_t)s * F_H))[lane];
        a0.x += h.x; a0.y += h.y; a0.z += h.z; a0.w += h.w;
    }
    float dv = dinv[v];
    float4 hv = ((const float4*)(Hs + (size_t)v * F_H))[lane];
    float4 b = ((const float4*)bias)[lane];
    float4 o;
    o.x = fmaxf(dv * (a0.x + a1.x + hv.x) + b.x, 0.0f);
    o.y = fmaxf(dv * (a0.y + a1.y + hv.y) + b.y, 0.0f);
    o.z = fmaxf(dv * (a0.z + a1.z + hv.z) + b.z, 0.0f);
    o.w = fmaxf(dv * (a0.w + a1.w + hv.w) + b.w, 0.0f);
    if constexpr (BF16OUT) {
        ushort4 ob;
        ob.x = f2bf(o.x); ob.y = f2bf(o.y); ob.z = f2bf(o.z); ob.w = f2bf(o.w);
        ((ushort4*)outp)[(size_t)v * 64 + lane] = ob;
    } else {
        ((float4*)outp)[(size_t)v * 64 + lane] = o;
    }
}

// ---------------------------------------------------------------- mean pool (sorted batch, no atomics)
__global__ __launch_bounds__(256) void k_pool(const float* __restrict__ h,
                                              const int* __restrict__ batch,
                                              float* __restrict__ hg) {
    int g = blockIdx.x;
    __shared__ int sBeg, sEnd;
    if (threadIdx.x == 0) {
        int lo = 0, hi = N_NODES;
        while (lo < hi) { int mid = (lo + hi) >> 1; if (batch[mid] < g) lo = mid + 1; else hi = mid; }
        sBeg = lo;
        hi = N_NODES;
        while (lo < hi) { int mid = (lo + hi) >> 1; if (batch[mid] < g + 1) lo = mid + 1; else hi = mid; }
        sEnd = lo;
    }
    __syncthreads();
    int beg = sBeg, end = sEnd;
    float acc = 0.0f;
    for (int v = beg; v < end; ++v) acc += h[(size_t)v * F_H + threadIdx.x];
    float c = fmaxf((float)(end - beg), 1.0f);
    hg[(size_t)g * F_H + threadIdx.x] = acc / c;
}

// ---------------------------------------------------------------- VAE head: mu, logvar, z
__global__ __launch_bounds__(256) void k_head(const float* __restrict__ hg,
                                              const float* __restrict__ Wmu,
                                              const float* __restrict__ bmu,
                                              const float* __restrict__ Wlv,
                                              const float* __restrict__ blv,
                                              const float* __restrict__ eps,
                                              float* __restrict__ out,
                                              float* __restrict__ z) {
    int i = blockIdx.x * blockDim.x + threadIdx.x;
    if (i >= N_GRAPHS * F_L) return;
    int g = i / F_L, l = i % F_L;
    const float* hr = hg + (size_t)g * F_H;
    float smu = 0.0f, slv = 0.0f;
    for (int k = 0; k < F_H; ++k) {
        float h = hr[k];
        smu += h * Wmu[k * F_L + l];
        slv += h * Wlv[k * F_L + l];
    }
    smu += bmu[l];
    slv += blv[l];
    out[MU_OFF + i] = smu;
    out[LV_OFF + i] = slv;
    z[i] = smu + eps[i] * expf(0.5f * slv);
}

// ---------------------------------------------------------------- adjacency expansion
__global__ __launch_bounds__(256) void k_adj(const float* __restrict__ probs,
                                             float* __restrict__ adj) {
    int i = blockIdx.x * blockDim.x + threadIdx.x;
    if (i >= ADJ_SIZE) return;
    int g = i / (MAXN * MAXN);
    int r = i % (MAXN * MAXN);
    int a = r / MAXN, b = r % MAXN;
    float v = 0.0f;
    if (a != b) {
        int lo = min(a, b), hi = max(a, b);
        int p = lo * (MAXN - 1) - (lo * (lo - 1)) / 2 + (hi - lo - 1);
        v = probs[(size_t)g * P_PAIRS + p];
    }
    adj[i] = v;
}

// ================================================================ launch
extern "C" void kernel_launch(void* const* d_in, const int* in_sizes, int n_in,
                              void* d_out, int out_size, void* d_ws, size_t ws_size,
                              hipStream_t stream) {
    const float* x    = (const float*)d_in[0];
    const int*   eidx = (const int*)d_in[1];
    const int*   batch= (const int*)d_in[2];
    const float* eps  = (const float*)d_in[3];
    const float* W1   = (const float*)d_in[4];
    const float* b1   = (const float*)d_in[5];
    const float* W2   = (const float*)d_in[6];
    const float* b2   = (const float*)d_in[7];
    const float* Wmu  = (const float*)d_in[8];
    const float* bmu  = (const float*)d_in[9];
    const float* Wlv  = (const float*)d_in[10];
    const float* blv  = (const float*)d_in[11];
    const float* D1   = (const float*)d_in[12];
    const float* db1  = (const float*)d_in[13];
    const float* D2   = (const float*)d_in[14];
    const float* db2  = (const float*)d_in[15];
    const float* D3   = (const float*)d_in[16];
    const float* db3  = (const float*)d_in[17];

    const int* src = eidx;
    const int* dst = eidx + N_EDGES;
    float* out = (float*)d_out;

    // workspace carve-up
    char* wsb = (char*)d_ws;
    size_t o = 0;
    auto carve = [&](size_t bytes) { void* p = wsb + o; o += (bytes + 255) & ~255ull; return p; };
    int*   deg    = (int*)  carve(N_NODES * sizeof(int));
    int*   fill   = (int*)  carve(N_NODES * sizeof(int));
    int*   rowptr = (int*)  carve((N_NODES + 1) * sizeof(int));
    int*   bsum   = (int*)  carve(128 * sizeof(int));
    int*   col    = (int*)  carve(N_EDGES * sizeof(int));
    float* dinv   = (float*)carve(N_NODES * sizeof(float));
    unsigned short* xb  = (unsigned short*)carve((size_t)N_NODES * F_IN * sizeof(short));
    unsigned short* W1p = (unsigned short*)carve((size_t)F_IN * F_H * sizeof(short));
    unsigned short* W2p = (unsigned short*)carve((size_t)F_H * F_H * sizeof(short));
    float* bufA   = (float*)carve((size_t)N_NODES * F_H * sizeof(float));           // Hs (fp32)
    unsigned short* h1b = (unsigned short*)carve((size_t)N_NODES * F_H * sizeof(short)); // h1 (bf16)
    float* bufC   = (float*)carve((size_t)N_NODES * F_H * sizeof(float));           // h2 (fp32)
    float* hg     = (float*)carve((size_t)N_GRAPHS * F_H * sizeof(float));
    float* z      = (float*)carve((size_t)N_GRAPHS * F_L * sizeof(float));
    float* d1     = (float*)carve((size_t)N_GRAPHS * F_H * sizeof(float));
    float* d2     = (float*)carve((size_t)N_GRAPHS * F_H * sizeof(float));
    float* probs  = (float*)carve((size_t)N_GRAPHS * P_PAIRS * sizeof(float));

    // ---- CSR build (shared by both layers)
    hipMemsetAsync(deg, 0, N_NODES * sizeof(int), stream);
    hipMemsetAsync(fill, 0, N_NODES * sizeof(int), stream);
    k_deg<<<ceil_div(N_EDGES, 256), 256, 0, stream>>>(dst, deg, N_EDGES);
    k_scan_local<<<SCAN_NB, 256, 0, stream>>>(deg, rowptr, bsum, N_NODES);
    k_scan_bsum<<<1, 128, 0, stream>>>(bsum, SCAN_NB);
    k_scan_add<<<SCAN_NB, 256, 0, stream>>>(rowptr, bsum, N_NODES);
    k_dinv<<<ceil_div(N_NODES, 256), 256, 0, stream>>>(deg, dinv, N_NODES);
    k_fill<<<ceil_div(N_EDGES, 256), 256, 0, stream>>>(src, dst, rowptr, fill, col, N_EDGES);

    // ---- bf16 casts + weight prepacks
    k_cvt<<<ceil_div(N_NODES * F_IN / 4, 256), 256, 0, stream>>>(x, xb, N_NODES * F_IN / 4);
    k_prepack<<<ceil_div(F_IN * F_H, 256), 256, 0, stream>>>(W1, W1p, F_IN, F_H);
    k_prepack<<<ceil_div(F_H * F_H, 256), 256, 0, stream>>>(W2, W2p, F_H, F_H);

    // ---- GCN layer 1: MFMA GEMM (dinv epilogue) + fused aggregate (bf16 out)
    {
        dim3 grid(F_H / 64, ceil_div(N_NODES, 128));
        k_gemm_mfma<F_IN><<<grid, 256, 0, stream>>>(xb, W1p, bufA, dinv, N_NODES, F_H);
    }
    k_gather<true><<<ceil_div(N_NODES, 4), 256, 0, stream>>>(bufA, rowptr, col, dinv, b1, h1b);

    // ---- GCN layer 2: MFMA GEMM + fused aggregate (fp32 out)
    {
        dim3 grid(F_H / 64, ceil_div(N_NODES, 128));
        k_gemm_mfma<F_H><<<grid, 256, 0, stream>>>(h1b, W2p, bufA, dinv, N_NODES, F_H);
    }
    k_gather<false><<<ceil_div(N_NODES, 4), 256, 0, stream>>>(bufA, rowptr, col, dinv, b2, bufC);

    // ---- global mean pool (sorted batch, atomic-free)
    k_pool<<<N_GRAPHS, 256, 0, stream>>>(bufC, batch, hg);

    // ---- VAE head + decoder (fp32)
    k_head<<<ceil_div(N_GRAPHS * F_L, 256), 256, 0, stream>>>(hg, Wmu, bmu, Wlv, blv, eps, out, z);
    {
        dim3 grid(ceil_div(F_H, 64), ceil_div(N_GRAPHS, 64));
        k_gemm_t<64, 64, 4, 4, 1><<<grid, 256, 0, stream>>>(z, D1, d1, N_GRAPHS, F_H, F_L, db1);
        k_gemm_t<64, 64, 4, 4, 1><<<grid, 256, 0, stream>>>(d1, D2, d2, N_GRAPHS, F_H, F_H, db2);
    }
    {
        dim3 grid(ceil_div(P_PAIRS, 64), ceil_div(N_GRAPHS, 64));
        k_gemm_t<64, 64, 4, 4, 2><<<grid, 256, 0, stream>>>(d2, D3, probs, N_GRAPHS, P_PAIRS, F_H, db3);
    }

    // ---- adjacency expansion
    k_adj<<<ceil_div(ADJ_SIZE, 256), 256, 0, stream>>>(probs, out);
}

// Round 6
// 309.199 us; speedup vs baseline: 8.8751x; 1.2115x over previous
//
#include <hip/hip_runtime.h>
#include <math.h>

#define N_NODES  20000
#define N_EDGES  320000
#define N_GRAPHS 200
#define MAXN     100
#define F_IN     128
#define F_H      256
#define F_L      64
#define P_PAIRS  4950
#define P_PAD    4992                       // P_PAIRS padded to multiple of 64
#define ADJ_SIZE (N_GRAPHS * MAXN * MAXN)   // 2,000,000
#define MU_OFF   ADJ_SIZE
#define LV_OFF   (ADJ_SIZE + N_GRAPHS * F_L)

#define SCAN_NB  ((N_NODES + 255) / 256)    // 79 blocks

static inline int ceil_div(int a, int b) { return (a + b - 1) / b; }

typedef __attribute__((ext_vector_type(8))) short bf16x8;   // 4 VGPRs
typedef __attribute__((ext_vector_type(4))) float f32x4;    // MFMA acc

// fp32 -> bf16 round-to-nearest-even
static __device__ inline unsigned short f2bf(float f) {
    union { float f; unsigned u; } v; v.f = f;
    unsigned r = (v.u + 0x7FFFu + ((v.u >> 16) & 1u)) >> 16;
    return (unsigned short)r;
}
static __device__ inline float bf2f(unsigned short s) {
    union { unsigned u; float f; } v; v.u = (unsigned)s << 16; return v.f;
}
static __device__ inline float4 ubf4(ushort4 u) {
    float4 f;
    f.x = bf2f(u.x); f.y = bf2f(u.y); f.z = bf2f(u.z); f.w = bf2f(u.w);
    return f;
}

// ---------------------------------------------------------------- degree histogram (int)
__global__ __launch_bounds__(256) void k_deg(const int* __restrict__ dst,
                                             int* __restrict__ deg, int nE) {
    int i = blockIdx.x * blockDim.x + threadIdx.x;
    if (i < nE) atomicAdd(deg + dst[i], 1);
}

// ---------------------------------------------------------------- 3-phase parallel scan (+dinv fused)
__global__ __launch_bounds__(256) void k_scan_local(const int* __restrict__ deg,
                                                    int* __restrict__ rowptr,
                                                    int* __restrict__ bsum,
                                                    float* __restrict__ dinv, int n) {
    __shared__ int tmp[256];
    int i = blockIdx.x * 256 + threadIdx.x;
    int v = (i < n) ? deg[i] : 0;
    if (i < n) dinv[i] = rsqrtf((float)v + 1.0f);   // +1 self-loop
    tmp[threadIdx.x] = v;
    __syncthreads();
    #pragma unroll
    for (int off = 1; off < 256; off <<= 1) {
        int t = (threadIdx.x >= (unsigned)off) ? tmp[threadIdx.x - off] : 0;
        __syncthreads();
        tmp[threadIdx.x] += t;
        __syncthreads();
    }
    if (i < n) rowptr[i + 1] = tmp[threadIdx.x];
    if (threadIdx.x == 255) bsum[blockIdx.x] = tmp[255];
}

__global__ __launch_bounds__(128) void k_scan_bsum(int* __restrict__ bsum, int nb) {
    __shared__ int tmp[128];
    int v = (threadIdx.x < nb) ? bsum[threadIdx.x] : 0;
    tmp[threadIdx.x] = v;
    __syncthreads();
    #pragma unroll
    for (int off = 1; off < 128; off <<= 1) {
        int t = (threadIdx.x >= (unsigned)off) ? tmp[threadIdx.x - off] : 0;
        __syncthreads();
        tmp[threadIdx.x] += t;
        __syncthreads();
    }
    if (threadIdx.x < nb) bsum[threadIdx.x] = tmp[threadIdx.x] - v;  // exclusive
}

__global__ __launch_bounds__(256) void k_scan_add(int* __restrict__ rowptr,
                                                  const int* __restrict__ bsum, int n) {
    int i = blockIdx.x * 256 + threadIdx.x;
    if (i < n) rowptr[i + 1] += bsum[blockIdx.x];
    if (blockIdx.x == 0 && threadIdx.x == 0) rowptr[0] = 0;
}

// ---------------------------------------------------------------- CSR fill
__global__ __launch_bounds__(256) void k_fill(const int* __restrict__ src,
                                              const int* __restrict__ dst,
                                              const int* __restrict__ rowptr,
                                              int* __restrict__ fill,
                                              int* __restrict__ col, int nE) {
    int e = blockIdx.x * blockDim.x + threadIdx.x;
    if (e >= nE) return;
    int d = dst[e];
    int pos = rowptr[d] + atomicAdd(fill + d, 1);
    col[pos] = src[e];
}

// ---------------------------------------------------------------- fp32 -> bf16 cast (vec4)
__global__ __launch_bounds__(256) void k_cvt(const float* __restrict__ in,
                                             unsigned short* __restrict__ out, int n4) {
    int i = blockIdx.x * blockDim.x + threadIdx.x;
    if (i >= n4) return;
    float4 v = ((const float4*)in)[i];
    ushort4 o;
    o.x = f2bf(v.x); o.y = f2bf(v.y); o.z = f2bf(v.z); o.w = f2bf(v.w);
    ((ushort4*)out)[i] = o;
}

// ---------------------------------------------------------------- fused weight prepack (5 matrices)
// B-fragment order: Bp[((kt*NT + nt)*64 + lane)*8 + j] = bf16(W[kt*32+(lane>>4)*8+j][nt*16+(lane&15)])
// Segments: W1(128x256), W2(256x256), D1(64x256), D2(256x256), D3(256x4950 pad 4992)
#define PP_S1 32768
#define PP_S2 98304
#define PP_S3 114688
#define PP_S4 180224
#define PP_END 1458176     // 180224 + 256*4992
__global__ __launch_bounds__(256) void k_prepack_all(
        const float* __restrict__ W1, const float* __restrict__ W2,
        const float* __restrict__ D1, const float* __restrict__ D2,
        const float* __restrict__ D3,
        unsigned short* __restrict__ W1p, unsigned short* __restrict__ W2p,
        unsigned short* __restrict__ D1p, unsigned short* __restrict__ D2p,
        unsigned short* __restrict__ D3p) {
    int tid = blockIdx.x * 256 + threadIdx.x;
    const float* W; unsigned short* Bp; int K, N, NP, t;
    if (tid < PP_S1)      { t = tid;          W = W1; Bp = W1p; K = 128; N = 256;  NP = 256; }
    else if (tid < PP_S2) { t = tid - PP_S1;  W = W2; Bp = W2p; K = 256; N = 256;  NP = 256; }
    else if (tid < PP_S3) { t = tid - PP_S2;  W = D1; Bp = D1p; K = 64;  N = 256;  NP = 256; }
    else if (tid < PP_S4) { t = tid - PP_S3;  W = D2; Bp = D2p; K = 256; N = 256;  NP = 256; }
    else if (tid < PP_END){ t = tid - PP_S4;  W = D3; Bp = D3p; K = 256; N = P_PAIRS; NP = P_PAD; }
    else return;
    int j    = t & 7;
    int lane = (t >> 3) & 63;
    int tile = t >> 9;
    int NT = NP >> 4;
    int nt = tile % NT;
    int kt = tile / NT;
    int k = kt * 32 + (lane >> 4) * 8 + j;
    int n = nt * 16 + (lane & 15);
    Bp[t] = (n < N) ? f2bf(W[(size_t)k * N + n]) : (unsigned short)0;
}

// ---------------------------------------------------------------- MFMA bf16 node GEMM
// C[M,N] = dinv[m] * (A[M,K]bf16 @ W[K,N]); LDS-free, barrier-free.
// Block: 256 thr = 4 waves; block tile 128 rows x 64 cols; wave tile 32x64.
template<int KDIM, bool BF16OUT>
__global__ __launch_bounds__(256) void k_gemm_mfma(const unsigned short* __restrict__ A,
                                                   const unsigned short* __restrict__ Bp,
                                                   void* __restrict__ C,
                                                   const float* __restrict__ dinv,
                                                   int M, int N) {
    constexpr int KT = KDIM / 32;
    const int NT   = N >> 4;
    const int lane = threadIdx.x & 63;
    const int wave = threadIdx.x >> 6;
    const int bm   = blockIdx.y * 128 + wave * 32;
    const int ng0  = blockIdx.x * 4;
    const int quad = lane >> 4;
    const int l15  = lane & 15;

    int m0 = bm + l15;
    int m1 = m0 + 16;
    int m0c = min(m0, M - 1), m1c = min(m1, M - 1);

    f32x4 acc[2][4];
    #pragma unroll
    for (int i = 0; i < 2; ++i)
        #pragma unroll
        for (int nt = 0; nt < 4; ++nt) acc[i][nt] = (f32x4){0.f, 0.f, 0.f, 0.f};

    #pragma unroll
    for (int kt = 0; kt < KT; ++kt) {
        bf16x8 a0 = *(const bf16x8*)(A + (size_t)m0c * KDIM + kt * 32 + quad * 8);
        bf16x8 a1 = *(const bf16x8*)(A + (size_t)m1c * KDIM + kt * 32 + quad * 8);
        #pragma unroll
        for (int nt = 0; nt < 4; ++nt) {
            bf16x8 b = *(const bf16x8*)(Bp + (((size_t)kt * NT + ng0 + nt) * 64 + lane) * 8);
            acc[0][nt] = __builtin_amdgcn_mfma_f32_16x16x32_bf16(a0, b, acc[0][nt], 0, 0, 0);
            acc[1][nt] = __builtin_amdgcn_mfma_f32_16x16x32_bf16(a1, b, acc[1][nt], 0, 0, 0);
        }
    }

    // C/D layout: col = lane&15, row = quad*4 + reg
    #pragma unroll
    for (int i = 0; i < 2; ++i) {
        #pragma unroll
        for (int r = 0; r < 4; ++r) {
            int gm = bm + i * 16 + quad * 4 + r;
            if (gm < M) {
                float dv = dinv[gm];
                if constexpr (BF16OUT) {
                    unsigned short* crow = (unsigned short*)C + (size_t)gm * N + (ng0 << 4);
                    #pragma unroll
                    for (int nt = 0; nt < 4; ++nt)
                        crow[nt * 16 + l15] = f2bf(acc[i][nt][r] * dv);
                } else {
                    float* crow = (float*)C + (size_t)gm * N + (ng0 << 4);
                    #pragma unroll
                    for (int nt = 0; nt < 4; ++nt)
                        crow[nt * 16 + l15] = acc[i][nt][r] * dv;
                }
            }
        }
    }
}

// ---------------------------------------------------------------- MFMA bf16 decoder GEMM
// Y = act(A[M,K]bf16 @ W[K,N] + bias); MODE 1: relu -> bf16 Y; MODE 2: sigmoid -> fp32 Y.
// Bp padded to NP cols; Y row stride = N (actual).
template<int KDIM, int MODE>
__global__ __launch_bounds__(256) void k_dec_mfma(const unsigned short* __restrict__ A,
                                                  const unsigned short* __restrict__ Bp,
                                                  void* __restrict__ Y,
                                                  const float* __restrict__ bias,
                                                  int M, int N, int NP) {
    constexpr int KT = KDIM / 32;
    const int NT   = NP >> 4;
    const int lane = threadIdx.x & 63;
    const int wave = threadIdx.x >> 6;
    const int bm   = blockIdx.y * 128 + wave * 32;
    const int ng0  = blockIdx.x * 4;
    const int quad = lane >> 4;
    const int l15  = lane & 15;

    int m0 = bm + l15;
    int m1 = m0 + 16;
    int m0c = min(m0, M - 1), m1c = min(m1, M - 1);

    f32x4 acc[2][4];
    #pragma unroll
    for (int i = 0; i < 2; ++i)
        #pragma unroll
        for (int nt = 0; nt < 4; ++nt) acc[i][nt] = (f32x4){0.f, 0.f, 0.f, 0.f};

    #pragma unroll
    for (int kt = 0; kt < KT; ++kt) {
        bf16x8 a0 = *(const bf16x8*)(A + (size_t)m0c * KDIM + kt * 32 + quad * 8);
        bf16x8 a1 = *(const bf16x8*)(A + (size_t)m1c * KDIM + kt * 32 + quad * 8);
        #pragma unroll
        for (int nt = 0; nt < 4; ++nt) {
            bf16x8 b = *(const bf16x8*)(Bp + (((size_t)kt * NT + ng0 + nt) * 64 + lane) * 8);
            acc[0][nt] = __builtin_amdgcn_mfma_f32_16x16x32_bf16(a0, b, acc[0][nt], 0, 0, 0);
            acc[1][nt] = __builtin_amdgcn_mfma_f32_16x16x32_bf16(a1, b, acc[1][nt], 0, 0, 0);
        }
    }

    #pragma unroll
    for (int i = 0; i < 2; ++i) {
        #pragma unroll
        for (int r = 0; r < 4; ++r) {
            int gm = bm + i * 16 + quad * 4 + r;
            if (gm >= M) continue;
            #pragma unroll
            for (int nt = 0; nt < 4; ++nt) {
                int gn = ((ng0 + nt) << 4) + l15;
                if (gn >= N) continue;
                float s = acc[i][nt][r] + bias[gn];
                if constexpr (MODE == 1) {
                    ((unsigned short*)Y)[(size_t)gm * N + gn] = f2bf(fmaxf(s, 0.0f));
                } else {
                    ((float*)Y)[(size_t)gm * N + gn] = 1.0f / (1.0f + expf(-s));
                }
            }
        }
    }
}

// ---------------------------------------------------------------- fused GCN aggregate (bf16 rows in)
// Hs[v] = dinv[v]*(A@W)[v] in bf16. out[v] = relu(dinv[v]*(sum Hs[s] + Hs[v]) + bias)
template<bool BF16OUT>
__global__ __launch_bounds__(256) void k_gather(const unsigned short* __restrict__ Hs,
                                                const int* __restrict__ rowptr,
                                                const int* __restrict__ col,
                                                const float* __restrict__ dinv,
                                                const float* __restrict__ bias,
                                                void* __restrict__ outp) {
    int v = blockIdx.x * 4 + (threadIdx.x >> 6);
    if (v >= N_NODES) return;
    int lane = threadIdx.x & 63;
    int beg = rowptr[v], end = rowptr[v + 1];
    float4 a0 = make_float4(0.f, 0.f, 0.f, 0.f);
    float4 a1 = make_float4(0.f, 0.f, 0.f, 0.f);
    int i = beg;
    for (; i + 4 <= end; i += 4) {
        int s0 = col[i + 0], s1 = col[i + 1], s2 = col[i + 2], s3 = col[i + 3];
        ushort4 u0 = ((const ushort4*)(Hs + (size_t)s0 * F_H))[lane];
        ushort4 u1 = ((const ushort4*)(Hs + (size_t)s1 * F_H))[lane];
        ushort4 u2 = ((const ushort4*)(Hs + (size_t)s2 * F_H))[lane];
        ushort4 u3 = ((const ushort4*)(Hs + (size_t)s3 * F_H))[lane];
        float4 h0 = ubf4(u0), h1 = ubf4(u1), h2 = ubf4(u2), h3 = ubf4(u3);
        a0.x += h0.x + h1.x; a0.y += h0.y + h1.y;
        a0.z += h0.z + h1.z; a0.w += h0.w + h1.w;
        a1.x += h2.x + h3.x; a1.y += h2.y + h3.y;
        a1.z += h2.z + h3.z; a1.w += h2.w + h3.w;
    }
    for (; i < end; ++i) {
        int s = col[i];
        float4 h = ubf4(((const ushort4*)(Hs + (size_t)s * F_H))[lane]);
        a0.x += h.x; a0.y += h.y; a0.z += h.z; a0.w += h.w;
    }
    float dv = dinv[v];
    float4 hv = ubf4(((const ushort4*)(Hs + (size_t)v * F_H))[lane]);
    float4 b = ((const float4*)bias)[lane];
    float4 o;
    o.x = fmaxf(dv * (a0.x + a1.x + hv.x) + b.x, 0.0f);
    o.y = fmaxf(dv * (a0.y + a1.y + hv.y) + b.y, 0.0f);
    o.z = fmaxf(dv * (a0.z + a1.z + hv.z) + b.z, 0.0f);
    o.w = fmaxf(dv * (a0.w + a1.w + hv.w) + b.w, 0.0f);
    if constexpr (BF16OUT) {
        ushort4 ob;
        ob.x = f2bf(o.x); ob.y = f2bf(o.y); ob.z = f2bf(o.z); ob.w = f2bf(o.w);
        ((ushort4*)outp)[(size_t)v * 64 + lane] = ob;
    } else {
        ((float4*)outp)[(size_t)v * 64 + lane] = o;
    }
}

// ---------------------------------------------------------------- mean pool (sorted batch, no atomics)
__global__ __launch_bounds__(256) void k_pool(const float* __restrict__ h,
                                              const int* __restrict__ batch,
                                              float* __restrict__ hg) {
    int g = blockIdx.x;
    __shared__ int sBeg, sEnd;
    if (threadIdx.x == 0) {
        int lo = 0, hi = N_NODES;
        while (lo < hi) { int mid = (lo + hi) >> 1; if (batch[mid] < g) lo = mid + 1; else hi = mid; }
        sBeg = lo;
        hi = N_NODES;
        while (lo < hi) { int mid = (lo + hi) >> 1; if (batch[mid] < g + 1) lo = mid + 1; else hi = mid; }
        sEnd = lo;
    }
    __syncthreads();
    int beg = sBeg, end = sEnd;
    float acc = 0.0f;
    for (int v = beg; v < end; ++v) acc += h[(size_t)v * F_H + threadIdx.x];
    float c = fmaxf((float)(end - beg), 1.0f);
    hg[(size_t)g * F_H + threadIdx.x] = acc / c;
}

// ---------------------------------------------------------------- VAE head: mu, logvar, z (bf16)
__global__ __launch_bounds__(256) void k_head(const float* __restrict__ hg,
                                              const float* __restrict__ Wmu,
                                              const float* __restrict__ bmu,
                                              const float* __restrict__ Wlv,
                                              const float* __restrict__ blv,
                                              const float* __restrict__ eps,
                                              float* __restrict__ out,
                                              unsigned short* __restrict__ zb) {
    int i = blockIdx.x * blockDim.x + threadIdx.x;
    if (i >= N_GRAPHS * F_L) return;
    int g = i / F_L, l = i % F_L;
    const float* hr = hg + (size_t)g * F_H;
    float smu = 0.0f, slv = 0.0f;
    for (int k = 0; k < F_H; ++k) {
        float h = hr[k];
        smu += h * Wmu[k * F_L + l];
        slv += h * Wlv[k * F_L + l];
    }
    smu += bmu[l];
    slv += blv[l];
    out[MU_OFF + i] = smu;
    out[LV_OFF + i] = slv;
    zb[i] = f2bf(smu + eps[i] * expf(0.5f * slv));
}

// ---------------------------------------------------------------- adjacency expansion
__global__ __launch_bounds__(256) void k_adj(const float* __restrict__ probs,
                                             float* __restrict__ adj) {
    int i = blockIdx.x * blockDim.x + threadIdx.x;
    if (i >= ADJ_SIZE) return;
    int g = i / (MAXN * MAXN);
    int r = i % (MAXN * MAXN);
    int a = r / MAXN, b = r % MAXN;
    float v = 0.0f;
    if (a != b) {
        int lo = min(a, b), hi = max(a, b);
        int p = lo * (MAXN - 1) - (lo * (lo - 1)) / 2 + (hi - lo - 1);
        v = probs[(size_t)g * P_PAIRS + p];
    }
    adj[i] = v;
}

// ================================================================ launch
extern "C" void kernel_launch(void* const* d_in, const int* in_sizes, int n_in,
                              void* d_out, int out_size, void* d_ws, size_t ws_size,
                              hipStream_t stream) {
    const float* x    = (const float*)d_in[0];
    const int*   eidx = (const int*)d_in[1];
    const int*   batch= (const int*)d_in[2];
    const float* eps  = (const float*)d_in[3];
    const float* W1   = (const float*)d_in[4];
    const float* b1   = (const float*)d_in[5];
    const float* W2   = (const float*)d_in[6];
    const float* b2   = (const float*)d_in[7];
    const float* Wmu  = (const float*)d_in[8];
    const float* bmu  = (const float*)d_in[9];
    const float* Wlv  = (const float*)d_in[10];
    const float* blv  = (const float*)d_in[11];
    const float* D1   = (const float*)d_in[12];
    const float* db1  = (const float*)d_in[13];
    const float* D2   = (const float*)d_in[14];
    const float* db2  = (const float*)d_in[15];
    const float* D3   = (const float*)d_in[16];
    const float* db3  = (const float*)d_in[17];

    const int* src = eidx;
    const int* dst = eidx + N_EDGES;
    float* out = (float*)d_out;

    // workspace carve-up
    char* wsb = (char*)d_ws;
    size_t o = 0;
    auto carve = [&](size_t bytes) { void* p = wsb + o; o += (bytes + 255) & ~255ull; return p; };
    int*   deg    = (int*)  carve(N_NODES * sizeof(int));   // contiguous with fill
    int*   fill   = (int*)  carve(N_NODES * sizeof(int));
    int*   rowptr = (int*)  carve((N_NODES + 1) * sizeof(int));
    int*   bsum   = (int*)  carve(128 * sizeof(int));
    int*   col    = (int*)  carve(N_EDGES * sizeof(int));
    float* dinv   = (float*)carve(N_NODES * sizeof(float));
    unsigned short* xb  = (unsigned short*)carve((size_t)N_NODES * F_IN * sizeof(short));
    unsigned short* W1p = (unsigned short*)carve((size_t)F_IN * F_H * sizeof(short));
    unsigned short* W2p = (unsigned short*)carve((size_t)F_H * F_H * sizeof(short));
    unsigned short* D1p = (unsigned short*)carve((size_t)F_L * F_H * sizeof(short));
    unsigned short* D2p = (unsigned short*)carve((size_t)F_H * F_H * sizeof(short));
    unsigned short* D3p = (unsigned short*)carve((size_t)F_H * P_PAD * sizeof(short));
    unsigned short* hs_b= (unsigned short*)carve((size_t)N_NODES * F_H * sizeof(short)); // Hs (bf16)
    unsigned short* h1b = (unsigned short*)carve((size_t)N_NODES * F_H * sizeof(short)); // h1 (bf16)
    float* bufC   = (float*)carve((size_t)N_NODES * F_H * sizeof(float));                // h2 (fp32)
    float* hg     = (float*)carve((size_t)N_GRAPHS * F_H * sizeof(float));
    unsigned short* zb  = (unsigned short*)carve((size_t)N_GRAPHS * F_L * sizeof(short));
    unsigned short* d1b = (unsigned short*)carve((size_t)N_GRAPHS * F_H * sizeof(short));
    unsigned short* d2b = (unsigned short*)carve((size_t)N_GRAPHS * F_H * sizeof(short));
    float* probs  = (float*)carve((size_t)N_GRAPHS * P_PAIRS * sizeof(float));

    // ---- CSR build (deg+fill zeroed in one contiguous memset: 2 x 80128-byte slots)
    hipMemsetAsync(deg, 0, 160256, stream);
    k_deg<<<ceil_div(N_EDGES, 256), 256, 0, stream>>>(dst, deg, N_EDGES);
    k_scan_local<<<SCAN_NB, 256, 0, stream>>>(deg, rowptr, bsum, dinv, N_NODES);
    k_scan_bsum<<<1, 128, 0, stream>>>(bsum, SCAN_NB);
    k_scan_add<<<SCAN_NB, 256, 0, stream>>>(rowptr, bsum, N_NODES);
    k_fill<<<ceil_div(N_EDGES, 256), 256, 0, stream>>>(src, dst, rowptr, fill, col, N_EDGES);

    // ---- bf16 casts + fused weight prepack
    k_cvt<<<ceil_div(N_NODES * F_IN / 4, 256), 256, 0, stream>>>(x, xb, N_NODES * F_IN / 4);
    k_prepack_all<<<PP_END / 256, 256, 0, stream>>>(W1, W2, D1, D2, D3,
                                                    W1p, W2p, D1p, D2p, D3p);

    // ---- GCN layer 1: MFMA GEMM (bf16 Hs out) + fused aggregate (bf16 out)
    {
        dim3 grid(F_H / 64, ceil_div(N_NODES, 128));
        k_gemm_mfma<F_IN, true><<<grid, 256, 0, stream>>>(xb, W1p, hs_b, dinv, N_NODES, F_H);
    }
    k_gather<true><<<ceil_div(N_NODES, 4), 256, 0, stream>>>(hs_b, rowptr, col, dinv, b1, h1b);

    // ---- GCN layer 2: MFMA GEMM (bf16 Hs out) + fused aggregate (fp32 out)
    {
        dim3 grid(F_H / 64, ceil_div(N_NODES, 128));
        k_gemm_mfma<F_H, true><<<grid, 256, 0, stream>>>(h1b, W2p, hs_b, dinv, N_NODES, F_H);
    }
    k_gather<false><<<ceil_div(N_NODES, 4), 256, 0, stream>>>(hs_b, rowptr, col, dinv, b2, bufC);

    // ---- global mean pool (sorted batch, atomic-free)
    k_pool<<<N_GRAPHS, 256, 0, stream>>>(bufC, batch, hg);

    // ---- VAE head (fp32 mu/lv out, bf16 z) + MFMA decoder
    k_head<<<ceil_div(N_GRAPHS * F_L, 256), 256, 0, stream>>>(hg, Wmu, bmu, Wlv, blv, eps, out, zb);
    {
        dim3 grid(F_H / 64, ceil_div(N_GRAPHS, 128));
        k_dec_mfma<F_L, 1><<<grid, 256, 0, stream>>>(zb, D1p, d1b, db1, N_GRAPHS, F_H, F_H);
        k_dec_mfma<F_H, 1><<<grid, 256, 0, stream>>>(d1b, D2p, d2b, db2, N_GRAPHS, F_H, F_H);
    }
    {
        dim3 grid(P_PAD / 64, ceil_div(N_GRAPHS, 128));
        k_dec_mfma<F_H, 2><<<grid, 256, 0, stream>>>(d2b, D3p, probs, db3, N_GRAPHS, P_PAIRS, P_PAD);
    }

    // ---- adjacency expansion
    k_adj<<<ceil_div(ADJ_SIZE, 256), 256, 0, stream>>>(probs, out);
}

// Round 7
// 276.668 us; speedup vs baseline: 9.9186x; 1.1176x over previous
//
#include <hip/hip_runtime.h>
#include <math.h>

#define N_NODES  20000
#define N_EDGES  320000
#define N_GRAPHS 200
#define MAXN     100
#define F_IN     128
#define F_H      256
#define F_L      64
#define P_PAIRS  4950
#define P_PAD    4992                       // P_PAIRS padded to multiple of 64
#define ADJ_SIZE (N_GRAPHS * MAXN * MAXN)   // 2,000,000
#define MU_OFF   ADJ_SIZE
#define LV_OFF   (ADJ_SIZE + N_GRAPHS * F_L)

#define SCAN_NB  ((N_NODES + 255) / 256)    // 79 blocks

static inline int ceil_div(int a, int b) { return (a + b - 1) / b; }

typedef __attribute__((ext_vector_type(8))) short bf16x8;   // 4 VGPRs
typedef __attribute__((ext_vector_type(4))) float f32x4;    // MFMA acc

// fp32 -> bf16 round-to-nearest-even
static __device__ inline unsigned short f2bf(float f) {
    union { float f; unsigned u; } v; v.f = f;
    unsigned r = (v.u + 0x7FFFu + ((v.u >> 16) & 1u)) >> 16;
    return (unsigned short)r;
}
static __device__ inline float bf2f(unsigned short s) {
    union { unsigned u; float f; } v; v.u = (unsigned)s << 16; return v.f;
}
static __device__ inline float4 ubf4(ushort4 u) {
    float4 f;
    f.x = bf2f(u.x); f.y = bf2f(u.y); f.z = bf2f(u.z); f.w = bf2f(u.w);
    return f;
}

// ---------------------------------------------------------------- degree histogram (int)
__global__ __launch_bounds__(256) void k_deg(const int* __restrict__ dst,
                                             int* __restrict__ deg, int nE) {
    int i = blockIdx.x * blockDim.x + threadIdx.x;
    if (i < nE) atomicAdd(deg + dst[i], 1);
}

// ---------------------------------------------------------------- 3-phase parallel scan (+dinv fused)
__global__ __launch_bounds__(256) void k_scan_local(const int* __restrict__ deg,
                                                    int* __restrict__ rowptr,
                                                    int* __restrict__ bsum,
                                                    float* __restrict__ dinv, int n) {
    __shared__ int tmp[256];
    int i = blockIdx.x * 256 + threadIdx.x;
    int v = (i < n) ? deg[i] : 0;
    if (i < n) dinv[i] = rsqrtf((float)v + 1.0f);   // +1 self-loop
    tmp[threadIdx.x] = v;
    __syncthreads();
    #pragma unroll
    for (int off = 1; off < 256; off <<= 1) {
        int t = (threadIdx.x >= (unsigned)off) ? tmp[threadIdx.x - off] : 0;
        __syncthreads();
        tmp[threadIdx.x] += t;
        __syncthreads();
    }
    if (i < n) rowptr[i + 1] = tmp[threadIdx.x];
    if (threadIdx.x == 255) bsum[blockIdx.x] = tmp[255];
}

__global__ __launch_bounds__(128) void k_scan_bsum(int* __restrict__ bsum, int nb) {
    __shared__ int tmp[128];
    int v = (threadIdx.x < nb) ? bsum[threadIdx.x] : 0;
    tmp[threadIdx.x] = v;
    __syncthreads();
    #pragma unroll
    for (int off = 1; off < 128; off <<= 1) {
        int t = (threadIdx.x >= (unsigned)off) ? tmp[threadIdx.x - off] : 0;
        __syncthreads();
        tmp[threadIdx.x] += t;
        __syncthreads();
    }
    if (threadIdx.x < nb) bsum[threadIdx.x] = tmp[threadIdx.x] - v;  // exclusive
}

__global__ __launch_bounds__(256) void k_scan_add(int* __restrict__ rowptr,
                                                  const int* __restrict__ bsum, int n) {
    int i = blockIdx.x * 256 + threadIdx.x;
    if (i < n) rowptr[i + 1] += bsum[blockIdx.x];
    if (blockIdx.x == 0 && threadIdx.x == 0) rowptr[0] = 0;
}

// ---------------------------------------------------------------- CSR fill
__global__ __launch_bounds__(256) void k_fill(const int* __restrict__ src,
                                              const int* __restrict__ dst,
                                              const int* __restrict__ rowptr,
                                              int* __restrict__ fill,
                                              int* __restrict__ col, int nE) {
    int e = blockIdx.x * blockDim.x + threadIdx.x;
    if (e >= nE) return;
    int d = dst[e];
    int pos = rowptr[d] + atomicAdd(fill + d, 1);
    col[pos] = src[e];
}

// ---------------------------------------------------------------- fused x-cast + weight prepack
// Segment 0: x fp32->bf16 (float4 granular). Then 5 prepack segments in
// B-fragment order: Bp[((kt*NT+nt)*64+lane)*8+j] = bf16(W[kt*32+(lane>>4)*8+j][nt*16+(lane&15)])
#define CV_END 640000      // N_NODES*F_IN/4
#define PP_S1 32768
#define PP_S2 98304
#define PP_S3 114688
#define PP_S4 180224
#define PP_END 1458176     // 180224 + 256*4992
__global__ __launch_bounds__(256) void k_cvt_prepack(
        const float* __restrict__ x, unsigned short* __restrict__ xb,
        const float* __restrict__ W1, const float* __restrict__ W2,
        const float* __restrict__ D1, const float* __restrict__ D2,
        const float* __restrict__ D3,
        unsigned short* __restrict__ W1p, unsigned short* __restrict__ W2p,
        unsigned short* __restrict__ D1p, unsigned short* __restrict__ D2p,
        unsigned short* __restrict__ D3p) {
    int tid = blockIdx.x * 256 + threadIdx.x;
    if (tid < CV_END) {
        float4 v = ((const float4*)x)[tid];
        ushort4 o;
        o.x = f2bf(v.x); o.y = f2bf(v.y); o.z = f2bf(v.z); o.w = f2bf(v.w);
        ((ushort4*)xb)[tid] = o;
        return;
    }
    int pid = tid - CV_END;
    const float* W; unsigned short* Bp; int N, NP, t;
    if (pid < PP_S1)      { t = pid;          W = W1; Bp = W1p; N = 256;     NP = 256; }
    else if (pid < PP_S2) { t = pid - PP_S1;  W = W2; Bp = W2p; N = 256;     NP = 256; }
    else if (pid < PP_S3) { t = pid - PP_S2;  W = D1; Bp = D1p; N = 256;     NP = 256; }
    else if (pid < PP_S4) { t = pid - PP_S3;  W = D2; Bp = D2p; N = 256;     NP = 256; }
    else if (pid < PP_END){ t = pid - PP_S4;  W = D3; Bp = D3p; N = P_PAIRS; NP = P_PAD; }
    else return;
    int j    = t & 7;
    int lane = (t >> 3) & 63;
    int tile = t >> 9;
    int NT = NP >> 4;
    int nt = tile % NT;
    int kt = tile / NT;
    int k = kt * 32 + (lane >> 4) * 8 + j;
    int n = nt * 16 + (lane & 15);
    Bp[t] = (n < N) ? f2bf(W[(size_t)k * N + n]) : (unsigned short)0;
}

// ---------------------------------------------------------------- MFMA bf16 node GEMM
// C[M,N] = dinv[m] * (A[M,K]bf16 @ W[K,N]); LDS-free, barrier-free.
// Block: 256 thr = 4 waves; block tile 128 rows x 64 cols; wave tile 32x64.
template<int KDIM, bool BF16OUT>
__global__ __launch_bounds__(256) void k_gemm_mfma(const unsigned short* __restrict__ A,
                                                   const unsigned short* __restrict__ Bp,
                                                   void* __restrict__ C,
                                                   const float* __restrict__ dinv,
                                                   int M, int N) {
    constexpr int KT = KDIM / 32;
    const int NT   = N >> 4;
    const int lane = threadIdx.x & 63;
    const int wave = threadIdx.x >> 6;
    const int bm   = blockIdx.y * 128 + wave * 32;
    const int ng0  = blockIdx.x * 4;
    const int quad = lane >> 4;
    const int l15  = lane & 15;

    int m0 = bm + l15;
    int m1 = m0 + 16;
    int m0c = min(m0, M - 1), m1c = min(m1, M - 1);

    f32x4 acc[2][4];
    #pragma unroll
    for (int i = 0; i < 2; ++i)
        #pragma unroll
        for (int nt = 0; nt < 4; ++nt) acc[i][nt] = (f32x4){0.f, 0.f, 0.f, 0.f};

    #pragma unroll
    for (int kt = 0; kt < KT; ++kt) {
        bf16x8 a0 = *(const bf16x8*)(A + (size_t)m0c * KDIM + kt * 32 + quad * 8);
        bf16x8 a1 = *(const bf16x8*)(A + (size_t)m1c * KDIM + kt * 32 + quad * 8);
        #pragma unroll
        for (int nt = 0; nt < 4; ++nt) {
            bf16x8 b = *(const bf16x8*)(Bp + (((size_t)kt * NT + ng0 + nt) * 64 + lane) * 8);
            acc[0][nt] = __builtin_amdgcn_mfma_f32_16x16x32_bf16(a0, b, acc[0][nt], 0, 0, 0);
            acc[1][nt] = __builtin_amdgcn_mfma_f32_16x16x32_bf16(a1, b, acc[1][nt], 0, 0, 0);
        }
    }

    // C/D layout: col = lane&15, row = quad*4 + reg
    #pragma unroll
    for (int i = 0; i < 2; ++i) {
        #pragma unroll
        for (int r = 0; r < 4; ++r) {
            int gm = bm + i * 16 + quad * 4 + r;
            if (gm < M) {
                float dv = dinv[gm];
                if constexpr (BF16OUT) {
                    unsigned short* crow = (unsigned short*)C + (size_t)gm * N + (ng0 << 4);
                    #pragma unroll
                    for (int nt = 0; nt < 4; ++nt)
                        crow[nt * 16 + l15] = f2bf(acc[i][nt][r] * dv);
                } else {
                    float* crow = (float*)C + (size_t)gm * N + (ng0 << 4);
                    #pragma unroll
                    for (int nt = 0; nt < 4; ++nt)
                        crow[nt * 16 + l15] = acc[i][nt][r] * dv;
                }
            }
        }
    }
}

// ---------------------------------------------------------------- MFMA bf16 decoder GEMM
// Y = act(A[M,K]bf16 @ W[K,N] + bias); MODE 1: relu -> bf16 Y; MODE 2: sigmoid -> fp32 Y.
template<int KDIM, int MODE>
__global__ __launch_bounds__(256) void k_dec_mfma(const unsigned short* __restrict__ A,
                                                  const unsigned short* __restrict__ Bp,
                                                  void* __restrict__ Y,
                                                  const float* __restrict__ bias,
                                                  int M, int N, int NP) {
    constexpr int KT = KDIM / 32;
    const int NT   = NP >> 4;
    const int lane = threadIdx.x & 63;
    const int wave = threadIdx.x >> 6;
    const int bm   = blockIdx.y * 128 + wave * 32;
    const int ng0  = blockIdx.x * 4;
    const int quad = lane >> 4;
    const int l15  = lane & 15;

    int m0 = bm + l15;
    int m1 = m0 + 16;
    int m0c = min(m0, M - 1), m1c = min(m1, M - 1);

    f32x4 acc[2][4];
    #pragma unroll
    for (int i = 0; i < 2; ++i)
        #pragma unroll
        for (int nt = 0; nt < 4; ++nt) acc[i][nt] = (f32x4){0.f, 0.f, 0.f, 0.f};

    #pragma unroll
    for (int kt = 0; kt < KT; ++kt) {
        bf16x8 a0 = *(const bf16x8*)(A + (size_t)m0c * KDIM + kt * 32 + quad * 8);
        bf16x8 a1 = *(const bf16x8*)(A + (size_t)m1c * KDIM + kt * 32 + quad * 8);
        #pragma unroll
        for (int nt = 0; nt < 4; ++nt) {
            bf16x8 b = *(const bf16x8*)(Bp + (((size_t)kt * NT + ng0 + nt) * 64 + lane) * 8);
            acc[0][nt] = __builtin_amdgcn_mfma_f32_16x16x32_bf16(a0, b, acc[0][nt], 0, 0, 0);
            acc[1][nt] = __builtin_amdgcn_mfma_f32_16x16x32_bf16(a1, b, acc[1][nt], 0, 0, 0);
        }
    }

    #pragma unroll
    for (int i = 0; i < 2; ++i) {
        #pragma unroll
        for (int r = 0; r < 4; ++r) {
            int gm = bm + i * 16 + quad * 4 + r;
            if (gm >= M) continue;
            #pragma unroll
            for (int nt = 0; nt < 4; ++nt) {
                int gn = ((ng0 + nt) << 4) + l15;
                if (gn >= N) continue;
                float s = acc[i][nt][r] + bias[gn];
                if constexpr (MODE == 1) {
                    ((unsigned short*)Y)[(size_t)gm * N + gn] = f2bf(fmaxf(s, 0.0f));
                } else {
                    ((float*)Y)[(size_t)gm * N + gn] = 1.0f / (1.0f + expf(-s));
                }
            }
        }
    }
}

// ---------------------------------------------------------------- fused GCN aggregate (bf16 rows in)
// Hs[v] = dinv[v]*(A@W)[v] in bf16. out[v] = relu(dinv[v]*(sum Hs[s] + Hs[v]) + bias)
// One wave per node, lane covers 4 feats; unroll 8 with 4 accumulators.
__global__ __launch_bounds__(256) void k_gather(const unsigned short* __restrict__ Hs,
                                                const int* __restrict__ rowptr,
                                                const int* __restrict__ col,
                                                const float* __restrict__ dinv,
                                                const float* __restrict__ bias,
                                                unsigned short* __restrict__ outp) {
    int v = blockIdx.x * 4 + (threadIdx.x >> 6);
    if (v >= N_NODES) return;
    int lane = threadIdx.x & 63;
    int beg = rowptr[v], end = rowptr[v + 1];
    float4 a0 = make_float4(0.f, 0.f, 0.f, 0.f);
    float4 a1 = make_float4(0.f, 0.f, 0.f, 0.f);
    float4 a2 = make_float4(0.f, 0.f, 0.f, 0.f);
    float4 a3 = make_float4(0.f, 0.f, 0.f, 0.f);
    int i = beg;
    for (; i + 8 <= end; i += 8) {
        int s0 = col[i + 0], s1 = col[i + 1], s2 = col[i + 2], s3 = col[i + 3];
        int s4 = col[i + 4], s5 = col[i + 5], s6 = col[i + 6], s7 = col[i + 7];
        float4 h0 = ubf4(((const ushort4*)(Hs + (size_t)s0 * F_H))[lane]);
        float4 h1 = ubf4(((const ushort4*)(Hs + (size_t)s1 * F_H))[lane]);
        float4 h2 = ubf4(((const ushort4*)(Hs + (size_t)s2 * F_H))[lane]);
        float4 h3 = ubf4(((const ushort4*)(Hs + (size_t)s3 * F_H))[lane]);
        float4 h4 = ubf4(((const ushort4*)(Hs + (size_t)s4 * F_H))[lane]);
        float4 h5 = ubf4(((const ushort4*)(Hs + (size_t)s5 * F_H))[lane]);
        float4 h6 = ubf4(((const ushort4*)(Hs + (size_t)s6 * F_H))[lane]);
        float4 h7 = ubf4(((const ushort4*)(Hs + (size_t)s7 * F_H))[lane]);
        a0.x += h0.x + h4.x; a0.y += h0.y + h4.y; a0.z += h0.z + h4.z; a0.w += h0.w + h4.w;
        a1.x += h1.x + h5.x; a1.y += h1.y + h5.y; a1.z += h1.z + h5.z; a1.w += h1.w + h5.w;
        a2.x += h2.x + h6.x; a2.y += h2.y + h6.y; a2.z += h2.z + h6.z; a2.w += h2.w + h6.w;
        a3.x += h3.x + h7.x; a3.y += h3.y + h7.y; a3.z += h3.z + h7.z; a3.w += h3.w + h7.w;
    }
    for (; i < end; ++i) {
        int s = col[i];
        float4 h = ubf4(((const ushort4*)(Hs + (size_t)s * F_H))[lane]);
        a0.x += h.x; a0.y += h.y; a0.z += h.z; a0.w += h.w;
    }
    float dv = dinv[v];
    float4 hv = ubf4(((const ushort4*)(Hs + (size_t)v * F_H))[lane]);
    float4 b = ((const float4*)bias)[lane];
    float4 o;
    o.x = fmaxf(dv * (a0.x + a1.x + a2.x + a3.x + hv.x) + b.x, 0.0f);
    o.y = fmaxf(dv * (a0.y + a1.y + a2.y + a3.y + hv.y) + b.y, 0.0f);
    o.z = fmaxf(dv * (a0.z + a1.z + a2.z + a3.z + hv.z) + b.z, 0.0f);
    o.w = fmaxf(dv * (a0.w + a1.w + a2.w + a3.w + hv.w) + b.w, 0.0f);
    ushort4 ob;
    ob.x = f2bf(o.x); ob.y = f2bf(o.y); ob.z = f2bf(o.z); ob.w = f2bf(o.w);
    ((ushort4*)outp)[(size_t)v * 64 + lane] = ob;
}

// ---------------------------------------------------------------- fused mean pool + VAE head
// One block per graph: pool h2 (bf16) into LDS, then mu/lv (fp32 out) and z (bf16).
__global__ __launch_bounds__(256) void k_pool_head(const unsigned short* __restrict__ h2b,
                                                   const int* __restrict__ batch,
                                                   const float* __restrict__ Wmu,
                                                   const float* __restrict__ bmu,
                                                   const float* __restrict__ Wlv,
                                                   const float* __restrict__ blv,
                                                   const float* __restrict__ eps,
                                                   float* __restrict__ out,
                                                   unsigned short* __restrict__ zb) {
    int g = blockIdx.x;
    int tid = threadIdx.x;
    __shared__ float hgs[F_H];
    __shared__ float mulv[128];
    __shared__ int sBeg, sEnd;
    if (tid == 0) {
        int lo = 0, hi = N_NODES;
        while (lo < hi) { int mid = (lo + hi) >> 1; if (batch[mid] < g) lo = mid + 1; else hi = mid; }
        sBeg = lo;
        hi = N_NODES;
        while (lo < hi) { int mid = (lo + hi) >> 1; if (batch[mid] < g + 1) lo = mid + 1; else hi = mid; }
        sEnd = lo;
    }
    __syncthreads();
    int beg = sBeg, end = sEnd;
    float acc = 0.0f;
    #pragma unroll 4
    for (int v = beg; v < end; ++v) acc += bf2f(h2b[(size_t)v * F_H + tid]);
    hgs[tid] = acc / fmaxf((float)(end - beg), 1.0f);
    __syncthreads();
    if (tid < 128) {
        int l = tid & 63;
        const float* W = (tid < 64) ? Wmu : Wlv;
        float s = 0.0f;
        #pragma unroll 8
        for (int k = 0; k < F_H; ++k) s += hgs[k] * W[k * F_L + l];
        s += (tid < 64) ? bmu[l] : blv[l];
        out[((tid < 64) ? MU_OFF : LV_OFF) + g * F_L + l] = s;
        mulv[tid] = s;
    }
    __syncthreads();
    if (tid < 64) {
        float mu = mulv[tid], lv = mulv[64 + tid];
        zb[g * F_L + tid] = f2bf(mu + eps[g * F_L + tid] * expf(0.5f * lv));
    }
}

// ---------------------------------------------------------------- adjacency expansion
__global__ __launch_bounds__(256) void k_adj(const float* __restrict__ probs,
                                             float* __restrict__ adj) {
    int i = blockIdx.x * blockDim.x + threadIdx.x;
    if (i >= ADJ_SIZE) return;
    int g = i / (MAXN * MAXN);
    int r = i % (MAXN * MAXN);
    int a = r / MAXN, b = r % MAXN;
    float v = 0.0f;
    if (a != b) {
        int lo = min(a, b), hi = max(a, b);
        int p = lo * (MAXN - 1) - (lo * (lo - 1)) / 2 + (hi - lo - 1);
        v = probs[(size_t)g * P_PAIRS + p];
    }
    adj[i] = v;
}

// ================================================================ launch
extern "C" void kernel_launch(void* const* d_in, const int* in_sizes, int n_in,
                              void* d_out, int out_size, void* d_ws, size_t ws_size,
                              hipStream_t stream) {
    const float* x    = (const float*)d_in[0];
    const int*   eidx = (const int*)d_in[1];
    const int*   batch= (const int*)d_in[2];
    const float* eps  = (const float*)d_in[3];
    const float* W1   = (const float*)d_in[4];
    const float* b1   = (const float*)d_in[5];
    const float* W2   = (const float*)d_in[6];
    const float* b2   = (const float*)d_in[7];
    const float* Wmu  = (const float*)d_in[8];
    const float* bmu  = (const float*)d_in[9];
    const float* Wlv  = (const float*)d_in[10];
    const float* blv  = (const float*)d_in[11];
    const float* D1   = (const float*)d_in[12];
    const float* db1  = (const float*)d_in[13];
    const float* D2   = (const float*)d_in[14];
    const float* db2  = (const float*)d_in[15];
    const float* D3   = (const float*)d_in[16];
    const float* db3  = (const float*)d_in[17];

    const int* src = eidx;
    const int* dst = eidx + N_EDGES;
    float* out = (float*)d_out;

    // workspace carve-up
    char* wsb = (char*)d_ws;
    size_t o = 0;
    auto carve = [&](size_t bytes) { void* p = wsb + o; o += (bytes + 255) & ~255ull; return p; };
    int*   deg    = (int*)  carve(N_NODES * sizeof(int));   // contiguous with fill
    int*   fill   = (int*)  carve(N_NODES * sizeof(int));
    int*   rowptr = (int*)  carve((N_NODES + 1) * sizeof(int));
    int*   bsum   = (int*)  carve(128 * sizeof(int));
    int*   col    = (int*)  carve(N_EDGES * sizeof(int));
    float* dinv   = (float*)carve(N_NODES * sizeof(float));
    unsigned short* xb  = (unsigned short*)carve((size_t)N_NODES * F_IN * sizeof(short));
    unsigned short* W1p = (unsigned short*)carve((size_t)F_IN * F_H * sizeof(short));
    unsigned short* W2p = (unsigned short*)carve((size_t)F_H * F_H * sizeof(short));
    unsigned short* D1p = (unsigned short*)carve((size_t)F_L * F_H * sizeof(short));
    unsigned short* D2p = (unsigned short*)carve((size_t)F_H * F_H * sizeof(short));
    unsigned short* D3p = (unsigned short*)carve((size_t)F_H * P_PAD * sizeof(short));
    unsigned short* hs_b= (unsigned short*)carve((size_t)N_NODES * F_H * sizeof(short)); // Hs (bf16)
    unsigned short* h1b = (unsigned short*)carve((size_t)N_NODES * F_H * sizeof(short)); // h1 (bf16)
    unsigned short* h2b = (unsigned short*)carve((size_t)N_NODES * F_H * sizeof(short)); // h2 (bf16)
    unsigned short* zb  = (unsigned short*)carve((size_t)N_GRAPHS * F_L * sizeof(short));
    unsigned short* d1b = (unsigned short*)carve((size_t)N_GRAPHS * F_H * sizeof(short));
    unsigned short* d2b = (unsigned short*)carve((size_t)N_GRAPHS * F_H * sizeof(short));
    float* probs  = (float*)carve((size_t)N_GRAPHS * P_PAIRS * sizeof(float));

    // ---- CSR build (deg+fill zeroed in one contiguous memset)
    hipMemsetAsync(deg, 0, 160256, stream);
    k_deg<<<ceil_div(N_EDGES, 256), 256, 0, stream>>>(dst, deg, N_EDGES);
    k_scan_local<<<SCAN_NB, 256, 0, stream>>>(deg, rowptr, bsum, dinv, N_NODES);
    k_scan_bsum<<<1, 128, 0, stream>>>(bsum, SCAN_NB);
    k_scan_add<<<SCAN_NB, 256, 0, stream>>>(rowptr, bsum, N_NODES);
    k_fill<<<ceil_div(N_EDGES, 256), 256, 0, stream>>>(src, dst, rowptr, fill, col, N_EDGES);

    // ---- fused x-cast + weight prepack
    k_cvt_prepack<<<ceil_div(CV_END + PP_END, 256), 256, 0, stream>>>(
        x, xb, W1, W2, D1, D2, D3, W1p, W2p, D1p, D2p, D3p);

    // ---- GCN layer 1: MFMA GEMM (bf16 Hs out) + fused aggregate (bf16 out)
    {
        dim3 grid(F_H / 64, ceil_div(N_NODES, 128));
        k_gemm_mfma<F_IN, true><<<grid, 256, 0, stream>>>(xb, W1p, hs_b, dinv, N_NODES, F_H);
    }
    k_gather<<<ceil_div(N_NODES, 4), 256, 0, stream>>>(hs_b, rowptr, col, dinv, b1, h1b);

    // ---- GCN layer 2: MFMA GEMM (bf16 Hs out) + fused aggregate (bf16 out)
    {
        dim3 grid(F_H / 64, ceil_div(N_NODES, 128));
        k_gemm_mfma<F_H, true><<<grid, 256, 0, stream>>>(h1b, W2p, hs_b, dinv, N_NODES, F_H);
    }
    k_gather<<<ceil_div(N_NODES, 4), 256, 0, stream>>>(hs_b, rowptr, col, dinv, b2, h2b);

    // ---- fused mean pool + VAE head (fp32 mu/lv out, bf16 z)
    k_pool_head<<<N_GRAPHS, 256, 0, stream>>>(h2b, batch, Wmu, bmu, Wlv, blv, eps, out, zb);

    // ---- MFMA decoder
    {
        dim3 grid(F_H / 64, ceil_div(N_GRAPHS, 128));
        k_dec_mfma<F_L, 1><<<grid, 256, 0, stream>>>(zb, D1p, d1b, db1, N_GRAPHS, F_H, F_H);
        k_dec_mfma<F_H, 1><<<grid, 256, 0, stream>>>(d1b, D2p, d2b, db2, N_GRAPHS, F_H, F_H);
    }
    {
        dim3 grid(P_PAD / 64, ceil_div(N_GRAPHS, 128));
        k_dec_mfma<F_H, 2><<<grid, 256, 0, stream>>>(d2b, D3p, probs, db3, N_GRAPHS, P_PAIRS, P_PAD);
    }

    // ---- adjacency expansion
    k_adj<<<ceil_div(ADJ_SIZE, 256), 256, 0, stream>>>(probs, out);
}

// Round 8
// 271.542 us; speedup vs baseline: 10.1058x; 1.0189x over previous
//
#include <hip/hip_runtime.h>
#include <math.h>

#define N_NODES  20000
#define N_EDGES  320000
#define N_GRAPHS 200
#define MAXN     100
#define F_IN     128
#define F_H      256
#define F_L      64
#define P_PAIRS  4950
#define P_PAD    4992                       // P_PAIRS padded to multiple of 64
#define ADJ_SIZE (N_GRAPHS * MAXN * MAXN)   // 2,000,000
#define MU_OFF   ADJ_SIZE
#define LV_OFF   (ADJ_SIZE + N_GRAPHS * F_L)

#define SCAN_NB  ((N_NODES + 255) / 256)    // 79 blocks

static inline int ceil_div(int a, int b) { return (a + b - 1) / b; }

typedef __attribute__((ext_vector_type(8))) short bf16x8;   // 4 VGPRs
typedef __attribute__((ext_vector_type(4))) float f32x4;    // MFMA acc

// fp32 -> bf16 round-to-nearest-even
static __device__ inline unsigned short f2bf(float f) {
    union { float f; unsigned u; } v; v.f = f;
    unsigned r = (v.u + 0x7FFFu + ((v.u >> 16) & 1u)) >> 16;
    return (unsigned short)r;
}
static __device__ inline float bf2f(unsigned short s) {
    union { unsigned u; float f; } v; v.u = (unsigned)s << 16; return v.f;
}
static __device__ inline float4 ubf4(ushort4 u) {
    float4 f;
    f.x = bf2f(u.x); f.y = bf2f(u.y); f.z = bf2f(u.z); f.w = bf2f(u.w);
    return f;
}

// ---------------------------------------------------------------- degree histogram (int)
__global__ __launch_bounds__(256) void k_deg(const int* __restrict__ dst,
                                             int* __restrict__ deg, int nE) {
    int i = blockIdx.x * blockDim.x + threadIdx.x;
    if (i < nE) atomicAdd(deg + dst[i], 1);
}

// ---------------------------------------------------------------- 2-phase parallel scan (+dinv fused)
// Phase A: per-block inclusive scan; rowptr[i+1] = local inclusive; bsum[b] = raw block total
__global__ __launch_bounds__(256) void k_scan_local(const int* __restrict__ deg,
                                                    int* __restrict__ rowptr,
                                                    int* __restrict__ bsum,
                                                    float* __restrict__ dinv, int n) {
    __shared__ int tmp[256];
    int i = blockIdx.x * 256 + threadIdx.x;
    int v = (i < n) ? deg[i] : 0;
    if (i < n) dinv[i] = rsqrtf((float)v + 1.0f);   // +1 self-loop
    tmp[threadIdx.x] = v;
    __syncthreads();
    #pragma unroll
    for (int off = 1; off < 256; off <<= 1) {
        int t = (threadIdx.x >= (unsigned)off) ? tmp[threadIdx.x - off] : 0;
        __syncthreads();
        tmp[threadIdx.x] += t;
        __syncthreads();
    }
    if (i < n) rowptr[i + 1] = tmp[threadIdx.x];
    if (threadIdx.x == 255) bsum[blockIdx.x] = tmp[255];
}

// Phase B (merged): each block reduces bsum[0..blockIdx) then adds the offset
__global__ __launch_bounds__(256) void k_scan_add(int* __restrict__ rowptr,
                                                  const int* __restrict__ bsum, int n) {
    __shared__ int red[256];
    int t = threadIdx.x;
    red[t] = (t < (int)blockIdx.x) ? bsum[t] : 0;   // SCAN_NB (79) < 256
    __syncthreads();
    #pragma unroll
    for (int off = 128; off > 0; off >>= 1) {
        if (t < off) red[t] += red[t + off];
        __syncthreads();
    }
    int offv = red[0];
    int i = blockIdx.x * 256 + t;
    if (i < n) rowptr[i + 1] += offv;
    if (blockIdx.x == 0 && t == 0) rowptr[0] = 0;
}

// ---------------------------------------------------------------- CSR fill
__global__ __launch_bounds__(256) void k_fill(const int* __restrict__ src,
                                              const int* __restrict__ dst,
                                              const int* __restrict__ rowptr,
                                              int* __restrict__ fill,
                                              int* __restrict__ col, int nE) {
    int e = blockIdx.x * blockDim.x + threadIdx.x;
    if (e >= nE) return;
    int d = dst[e];
    int pos = rowptr[d] + atomicAdd(fill + d, 1);
    col[pos] = src[e];
}

// ---------------------------------------------------------------- fused xs-cast + weight prepack
// Segment 0: xs[v][f] = bf16(dinv[v]*x[v][f]) (float4 granular).
// Then prepack W1, W2, D3 into B-fragment order:
//   Bp[((kt*NT+nt)*64+lane)*8+j] = bf16(W[kt*32+(lane>>4)*8+j][nt*16+(lane&15)])
#define CV_END 640000                      // N_NODES*F_IN/4
#define PP_S1  32768                       // W1: 128*256
#define PP_S2  98304                       // + W2: 256*256
#define PP_END 1376256                     // + D3: 256*4992
__global__ __launch_bounds__(256) void k_cvt_prepack(
        const float* __restrict__ x, const float* __restrict__ dinv,
        unsigned short* __restrict__ xs,
        const float* __restrict__ W1, const float* __restrict__ W2,
        const float* __restrict__ D3,
        unsigned short* __restrict__ W1p, unsigned short* __restrict__ W2p,
        unsigned short* __restrict__ D3p) {
    int tid = blockIdx.x * 256 + threadIdx.x;
    if (tid < CV_END) {
        int v = tid >> 5;                  // 32 float4 per row of 128
        float dv = dinv[v];
        float4 val = ((const float4*)x)[tid];
        ushort4 o;
        o.x = f2bf(val.x * dv); o.y = f2bf(val.y * dv);
        o.z = f2bf(val.z * dv); o.w = f2bf(val.w * dv);
        ((ushort4*)xs)[tid] = o;
        return;
    }
    int pid = tid - CV_END;
    const float* W; unsigned short* Bp; int N, NP, t;
    if (pid < PP_S1)      { t = pid;          W = W1; Bp = W1p; N = 256;     NP = 256; }
    else if (pid < PP_S2) { t = pid - PP_S1;  W = W2; Bp = W2p; N = 256;     NP = 256; }
    else if (pid < PP_END){ t = pid - PP_S2;  W = D3; Bp = D3p; N = P_PAIRS; NP = P_PAD; }
    else return;
    int j    = t & 7;
    int lane = (t >> 3) & 63;
    int tile = t >> 9;
    int NT = NP >> 4;
    int nt = tile % NT;
    int kt = tile / NT;
    int k = kt * 32 + (lane >> 4) * 8 + j;
    int n = nt * 16 + (lane & 15);
    Bp[t] = (n < N) ? f2bf(W[(size_t)k * N + n]) : (unsigned short)0;
}

// ---------------------------------------------------------------- unified MFMA bf16 GEMM
// Y = epi(A[M,K]bf16 @ Bp + bias); LDS-free, barrier-free; wave tile 32x64, block 128x64.
// MODE 1: relu -> bf16         (layer-2: h2)
// MODE 2: relu * dinv[m] -> bf16 (layer-1: h1s, pre-scaled for gather)
// MODE 3: sigmoid -> fp32      (decoder D3)
template<int KDIM, int MODE>
__global__ __launch_bounds__(256) void k_gemm(const unsigned short* __restrict__ A,
                                              const unsigned short* __restrict__ Bp,
                                              void* __restrict__ Y,
                                              const float* __restrict__ bias,
                                              const float* __restrict__ dinv,
                                              int M, int N, int NP) {
    constexpr int KT = KDIM / 32;
    const int NT   = NP >> 4;
    const int lane = threadIdx.x & 63;
    const int wave = threadIdx.x >> 6;
    const int bm   = blockIdx.y * 128 + wave * 32;
    const int ng0  = blockIdx.x * 4;
    const int quad = lane >> 4;
    const int l15  = lane & 15;

    int m0 = bm + l15;
    int m1 = m0 + 16;
    int m0c = min(m0, M - 1), m1c = min(m1, M - 1);

    f32x4 acc[2][4];
    #pragma unroll
    for (int i = 0; i < 2; ++i)
        #pragma unroll
        for (int nt = 0; nt < 4; ++nt) acc[i][nt] = (f32x4){0.f, 0.f, 0.f, 0.f};

    #pragma unroll
    for (int kt = 0; kt < KT; ++kt) {
        bf16x8 a0 = *(const bf16x8*)(A + (size_t)m0c * KDIM + kt * 32 + quad * 8);
        bf16x8 a1 = *(const bf16x8*)(A + (size_t)m1c * KDIM + kt * 32 + quad * 8);
        #pragma unroll
        for (int nt = 0; nt < 4; ++nt) {
            bf16x8 b = *(const bf16x8*)(Bp + (((size_t)kt * NT + ng0 + nt) * 64 + lane) * 8);
            acc[0][nt] = __builtin_amdgcn_mfma_f32_16x16x32_bf16(a0, b, acc[0][nt], 0, 0, 0);
            acc[1][nt] = __builtin_amdgcn_mfma_f32_16x16x32_bf16(a1, b, acc[1][nt], 0, 0, 0);
        }
    }

    // C/D layout: col = lane&15, row = quad*4 + reg
    #pragma unroll
    for (int i = 0; i < 2; ++i) {
        #pragma unroll
        for (int r = 0; r < 4; ++r) {
            int gm = bm + i * 16 + quad * 4 + r;
            if (gm >= M) continue;
            float dv = (MODE == 2) ? dinv[gm] : 1.0f;
            #pragma unroll
            for (int nt = 0; nt < 4; ++nt) {
                int gn = ((ng0 + nt) << 4) + l15;
                if (gn >= N) continue;
                float s = acc[i][nt][r] + bias[gn];
                if constexpr (MODE == 1) {
                    ((unsigned short*)Y)[(size_t)gm * N + gn] = f2bf(fmaxf(s, 0.0f));
                } else if constexpr (MODE == 2) {
                    ((unsigned short*)Y)[(size_t)gm * N + gn] = f2bf(fmaxf(s, 0.0f) * dv);
                } else {
                    ((float*)Y)[(size_t)gm * N + gn] = 1.0f / (1.0f + expf(-s));
                }
            }
        }
    }
}

// ---------------------------------------------------------------- gather layer 1 (128 feats)
// g1[v] = dinv[v] * (sum_{s in N(v)} xs[s] + xs[v]);  xs pre-scaled by dinv.
// One wave per node; lane covers 2 bf16 (ushort2); unroll 8, 4 accumulators.
__global__ __launch_bounds__(256) void k_gather1(const unsigned short* __restrict__ xs,
                                                 const int* __restrict__ rowptr,
                                                 const int* __restrict__ col,
                                                 const float* __restrict__ dinv,
                                                 unsigned short* __restrict__ outp) {
    int v = blockIdx.x * 4 + (threadIdx.x >> 6);
    if (v >= N_NODES) return;
    int lane = threadIdx.x & 63;
    int beg = rowptr[v], end = rowptr[v + 1];
    float2 a0 = make_float2(0.f, 0.f), a1 = make_float2(0.f, 0.f);
    float2 a2 = make_float2(0.f, 0.f), a3 = make_float2(0.f, 0.f);
    int i = beg;
    for (; i + 8 <= end; i += 8) {
        int s0 = col[i + 0], s1 = col[i + 1], s2 = col[i + 2], s3 = col[i + 3];
        int s4 = col[i + 4], s5 = col[i + 5], s6 = col[i + 6], s7 = col[i + 7];
        ushort2 u0 = ((const ushort2*)(xs + (size_t)s0 * F_IN))[lane];
        ushort2 u1 = ((const ushort2*)(xs + (size_t)s1 * F_IN))[lane];
        ushort2 u2 = ((const ushort2*)(xs + (size_t)s2 * F_IN))[lane];
        ushort2 u3 = ((const ushort2*)(xs + (size_t)s3 * F_IN))[lane];
        ushort2 u4 = ((const ushort2*)(xs + (size_t)s4 * F_IN))[lane];
        ushort2 u5 = ((const ushort2*)(xs + (size_t)s5 * F_IN))[lane];
        ushort2 u6 = ((const ushort2*)(xs + (size_t)s6 * F_IN))[lane];
        ushort2 u7 = ((const ushort2*)(xs + (size_t)s7 * F_IN))[lane];
        a0.x += bf2f(u0.x) + bf2f(u4.x); a0.y += bf2f(u0.y) + bf2f(u4.y);
        a1.x += bf2f(u1.x) + bf2f(u5.x); a1.y += bf2f(u1.y) + bf2f(u5.y);
        a2.x += bf2f(u2.x) + bf2f(u6.x); a2.y += bf2f(u2.y) + bf2f(u6.y);
        a3.x += bf2f(u3.x) + bf2f(u7.x); a3.y += bf2f(u3.y) + bf2f(u7.y);
    }
    for (; i < end; ++i) {
        int s = col[i];
        ushort2 u = ((const ushort2*)(xs + (size_t)s * F_IN))[lane];
        a0.x += bf2f(u.x); a0.y += bf2f(u.y);
    }
    float dv = dinv[v];
    ushort2 uv = ((const ushort2*)(xs + (size_t)v * F_IN))[lane];
    float ox = dv * (a0.x + a1.x + a2.x + a3.x + bf2f(uv.x));
    float oy = dv * (a0.y + a1.y + a2.y + a3.y + bf2f(uv.y));
    ushort2 ob; ob.x = f2bf(ox); ob.y = f2bf(oy);
    ((ushort2*)outp)[(size_t)v * 64 + lane] = ob;
}

// ---------------------------------------------------------------- gather layer 2 (256 feats)
// g2[v] = dinv[v] * (sum h1s[s] + h1s[v]);  h1s pre-scaled by dinv (GEMM epilogue).
__global__ __launch_bounds__(256) void k_gather2(const unsigned short* __restrict__ Hs,
                                                 const int* __restrict__ rowptr,
                                                 const int* __restrict__ col,
                                                 const float* __restrict__ dinv,
                                                 unsigned short* __restrict__ outp) {
    int v = blockIdx.x * 4 + (threadIdx.x >> 6);
    if (v >= N_NODES) return;
    int lane = threadIdx.x & 63;
    int beg = rowptr[v], end = rowptr[v + 1];
    float4 a0 = make_float4(0.f, 0.f, 0.f, 0.f);
    float4 a1 = make_float4(0.f, 0.f, 0.f, 0.f);
    float4 a2 = make_float4(0.f, 0.f, 0.f, 0.f);
    float4 a3 = make_float4(0.f, 0.f, 0.f, 0.f);
    int i = beg;
    for (; i + 8 <= end; i += 8) {
        int s0 = col[i + 0], s1 = col[i + 1], s2 = col[i + 2], s3 = col[i + 3];
        int s4 = col[i + 4], s5 = col[i + 5], s6 = col[i + 6], s7 = col[i + 7];
        float4 h0 = ubf4(((const ushort4*)(Hs + (size_t)s0 * F_H))[lane]);
        float4 h1 = ubf4(((const ushort4*)(Hs + (size_t)s1 * F_H))[lane]);
        float4 h2 = ubf4(((const ushort4*)(Hs + (size_t)s2 * F_H))[lane]);
        float4 h3 = ubf4(((const ushort4*)(Hs + (size_t)s3 * F_H))[lane]);
        float4 h4 = ubf4(((const ushort4*)(Hs + (size_t)s4 * F_H))[lane]);
        float4 h5 = ubf4(((const ushort4*)(Hs + (size_t)s5 * F_H))[lane]);
        float4 h6 = ubf4(((const ushort4*)(Hs + (size_t)s6 * F_H))[lane]);
        float4 h7 = ubf4(((const ushort4*)(Hs + (size_t)s7 * F_H))[lane]);
        a0.x += h0.x + h4.x; a0.y += h0.y + h4.y; a0.z += h0.z + h4.z; a0.w += h0.w + h4.w;
        a1.x += h1.x + h5.x; a1.y += h1.y + h5.y; a1.z += h1.z + h5.z; a1.w += h1.w + h5.w;
        a2.x += h2.x + h6.x; a2.y += h2.y + h6.y; a2.z += h2.z + h6.z; a2.w += h2.w + h6.w;
        a3.x += h3.x + h7.x; a3.y += h3.y + h7.y; a3.z += h3.z + h7.z; a3.w += h3.w + h7.w;
    }
    for (; i < end; ++i) {
        int s = col[i];
        float4 h = ubf4(((const ushort4*)(Hs + (size_t)s * F_H))[lane]);
        a0.x += h.x; a0.y += h.y; a0.z += h.z; a0.w += h.w;
    }
    float dv = dinv[v];
    float4 hv = ubf4(((const ushort4*)(Hs + (size_t)v * F_H))[lane]);
    float ox = dv * (a0.x + a1.x + a2.x + a3.x + hv.x);
    float oy = dv * (a0.y + a1.y + a2.y + a3.y + hv.y);
    float oz = dv * (a0.z + a1.z + a2.z + a3.z + hv.z);
    float ow = dv * (a0.w + a1.w + a2.w + a3.w + hv.w);
    ushort4 ob;
    ob.x = f2bf(ox); ob.y = f2bf(oy); ob.z = f2bf(oz); ob.w = f2bf(ow);
    ((ushort4*)outp)[(size_t)v * 64 + lane] = ob;
}

// ---------------------------------------------------------------- fused pool + head + dec1 + dec2
// One block per graph: mean-pool h2 (bf16) -> LDS, mu/logvar (fp32 out), z, d1, d2 (bf16 out).
__global__ __launch_bounds__(256) void k_pool_head_dec(const unsigned short* __restrict__ h2b,
                                                       const int* __restrict__ batch,
                                                       const float* __restrict__ Wmu,
                                                       const float* __restrict__ bmu,
                                                       const float* __restrict__ Wlv,
                                                       const float* __restrict__ blv,
                                                       const float* __restrict__ eps,
                                                       const float* __restrict__ D1,
                                                       const float* __restrict__ db1,
                                                       const float* __restrict__ D2,
                                                       const float* __restrict__ db2,
                                                       float* __restrict__ out,
                                                       unsigned short* __restrict__ d2b) {
    int g = blockIdx.x;
    int tid = threadIdx.x;
    __shared__ float hgs[F_H];
    __shared__ float mulv[128];
    __shared__ float zs[F_L];
    __shared__ float d1s[F_H];
    __shared__ int sBeg, sEnd;
    if (tid == 0) {
        int lo = 0, hi = N_NODES;
        while (lo < hi) { int mid = (lo + hi) >> 1; if (batch[mid] < g) lo = mid + 1; else hi = mid; }
        sBeg = lo;
        hi = N_NODES;
        while (lo < hi) { int mid = (lo + hi) >> 1; if (batch[mid] < g + 1) lo = mid + 1; else hi = mid; }
        sEnd = lo;
    }
    __syncthreads();
    int beg = sBeg, end = sEnd;
    float acc = 0.0f;
    #pragma unroll 4
    for (int v = beg; v < end; ++v) acc += bf2f(h2b[(size_t)v * F_H + tid]);
    hgs[tid] = acc / fmaxf((float)(end - beg), 1.0f);
    __syncthreads();
    if (tid < 128) {
        int l = tid & 63;
        const float* W = (tid < 64) ? Wmu : Wlv;
        float s = 0.0f;
        #pragma unroll 8
        for (int k = 0; k < F_H; ++k) s += hgs[k] * W[k * F_L + l];
        s += (tid < 64) ? bmu[l] : blv[l];
        out[((tid < 64) ? MU_OFF : LV_OFF) + g * F_L + l] = s;
        mulv[tid] = s;
    }
    __syncthreads();
    if (tid < 64) {
        float mu = mulv[tid], lv = mulv[64 + tid];
        zs[tid] = mu + eps[g * F_L + tid] * expf(0.5f * lv);
    }
    __syncthreads();
    {   // d1 = relu(z @ D1 + db1): K=64, coalesced D1 reads across threads
        float s = db1[tid];
        #pragma unroll 8
        for (int k = 0; k < F_L; ++k) s += zs[k] * D1[(size_t)k * F_H + tid];
        d1s[tid] = fmaxf(s, 0.0f);
    }
    __syncthreads();
    {   // d2 = relu(d1 @ D2 + db2): K=256
        float s = db2[tid];
        #pragma unroll 8
        for (int k = 0; k < F_H; ++k) s += d1s[k] * D2[(size_t)k * F_H + tid];
        d2b[(size_t)g * F_H + tid] = f2bf(fmaxf(s, 0.0f));
    }
}

// ---------------------------------------------------------------- adjacency expansion
__global__ __launch_bounds__(256) void k_adj(const float* __restrict__ probs,
                                             float* __restrict__ adj) {
    int i = blockIdx.x * blockDim.x + threadIdx.x;
    if (i >= ADJ_SIZE) return;
    int g = i / (MAXN * MAXN);
    int r = i % (MAXN * MAXN);
    int a = r / MAXN, b = r % MAXN;
    float v = 0.0f;
    if (a != b) {
        int lo = min(a, b), hi = max(a, b);
        int p = lo * (MAXN - 1) - (lo * (lo - 1)) / 2 + (hi - lo - 1);
        v = probs[(size_t)g * P_PAIRS + p];
    }
    adj[i] = v;
}

// ================================================================ launch
extern "C" void kernel_launch(void* const* d_in, const int* in_sizes, int n_in,
                              void* d_out, int out_size, void* d_ws, size_t ws_size,
                              hipStream_t stream) {
    const float* x    = (const float*)d_in[0];
    const int*   eidx = (const int*)d_in[1];
    const int*   batch= (const int*)d_in[2];
    const float* eps  = (const float*)d_in[3];
    const float* W1   = (const float*)d_in[4];
    const float* b1   = (const float*)d_in[5];
    const float* W2   = (const float*)d_in[6];
    const float* b2   = (const float*)d_in[7];
    const float* Wmu  = (const float*)d_in[8];
    const float* bmu  = (const float*)d_in[9];
    const float* Wlv  = (const float*)d_in[10];
    const float* blv  = (const float*)d_in[11];
    const float* D1   = (const float*)d_in[12];
    const float* db1  = (const float*)d_in[13];
    const float* D2   = (const float*)d_in[14];
    const float* db2  = (const float*)d_in[15];
    const float* D3   = (const float*)d_in[16];
    const float* db3  = (const float*)d_in[17];

    const int* src = eidx;
    const int* dst = eidx + N_EDGES;
    float* out = (float*)d_out;

    // workspace carve-up
    char* wsb = (char*)d_ws;
    size_t o = 0;
    auto carve = [&](size_t bytes) { void* p = wsb + o; o += (bytes + 255) & ~255ull; return p; };
    int*   deg    = (int*)  carve(N_NODES * sizeof(int));   // contiguous with fill
    int*   fill   = (int*)  carve(N_NODES * sizeof(int));
    int*   rowptr = (int*)  carve((N_NODES + 1) * sizeof(int));
    int*   bsum   = (int*)  carve(128 * sizeof(int));
    int*   col    = (int*)  carve(N_EDGES * sizeof(int));
    float* dinv   = (float*)carve(N_NODES * sizeof(float));
    unsigned short* xs  = (unsigned short*)carve((size_t)N_NODES * F_IN * sizeof(short));
    unsigned short* W1p = (unsigned short*)carve((size_t)F_IN * F_H * sizeof(short));
    unsigned short* W2p = (unsigned short*)carve((size_t)F_H * F_H * sizeof(short));
    unsigned short* D3p = (unsigned short*)carve((size_t)F_H * P_PAD * sizeof(short));
    unsigned short* g1  = (unsigned short*)carve((size_t)N_NODES * F_IN * sizeof(short)); // agg x
    unsigned short* h1s = (unsigned short*)carve((size_t)N_NODES * F_H * sizeof(short));  // dinv*h1
    unsigned short* g2  = (unsigned short*)carve((size_t)N_NODES * F_H * sizeof(short));  // agg h1
    unsigned short* h2b = (unsigned short*)carve((size_t)N_NODES * F_H * sizeof(short));  // h2
    unsigned short* d2b = (unsigned short*)carve((size_t)N_GRAPHS * F_H * sizeof(short));
    float* probs  = (float*)carve((size_t)N_GRAPHS * P_PAIRS * sizeof(float));

    // ---- CSR build (deg+fill zeroed in one contiguous memset)
    hipMemsetAsync(deg, 0, 160256, stream);
    k_deg<<<ceil_div(N_EDGES, 256), 256, 0, stream>>>(dst, deg, N_EDGES);
    k_scan_local<<<SCAN_NB, 256, 0, stream>>>(deg, rowptr, bsum, dinv, N_NODES);
    k_scan_add<<<SCAN_NB, 256, 0, stream>>>(rowptr, bsum, N_NODES);
    k_fill<<<ceil_div(N_EDGES, 256), 256, 0, stream>>>(src, dst, rowptr, fill, col, N_EDGES);

    // ---- fused xs-cast (dinv-scaled) + weight prepack
    k_cvt_prepack<<<ceil_div(CV_END + PP_END - CV_END + CV_END, 256), 256, 0, stream>>>(
        x, dinv, xs, W1, W2, D3, W1p, W2p, D3p);

    // ---- GCN layer 1: aggregate x first (128 feats), then MFMA transform
    k_gather1<<<ceil_div(N_NODES, 4), 256, 0, stream>>>(xs, rowptr, col, dinv, g1);
    {
        dim3 grid(F_H / 64, ceil_div(N_NODES, 128));
        k_gemm<F_IN, 2><<<grid, 256, 0, stream>>>(g1, W1p, h1s, b1, dinv, N_NODES, F_H, F_H);
    }

    // ---- GCN layer 2: aggregate h1s (256 feats), then MFMA transform
    k_gather2<<<ceil_div(N_NODES, 4), 256, 0, stream>>>(h1s, rowptr, col, dinv, g2);
    {
        dim3 grid(F_H / 64, ceil_div(N_NODES, 128));
        k_gemm<F_H, 1><<<grid, 256, 0, stream>>>(g2, W2p, h2b, b2, nullptr, N_NODES, F_H, F_H);
    }

    // ---- fused mean pool + head + dec1 + dec2
    k_pool_head_dec<<<N_GRAPHS, 256, 0, stream>>>(h2b, batch, Wmu, bmu, Wlv, blv, eps,
                                                  D1, db1, D2, db2, out, d2b);

    // ---- decoder D3 (MFMA, sigmoid)
    {
        dim3 grid(P_PAD / 64, ceil_div(N_GRAPHS, 128));
        k_gemm<F_H, 3><<<grid, 256, 0, stream>>>(d2b, D3p, probs, db3, nullptr,
                                                 N_GRAPHS, P_PAIRS, P_PAD);
    }

    // ---- adjacency expansion
    k_adj<<<ceil_div(ADJ_SIZE, 256), 256, 0, stream>>>(probs, out);
}